// Round 1
// baseline (814.398 us; speedup 1.0000x reference)
//
#include <hip/hip_runtime.h>

#define N_NODES 50000
#define N_EDGES 800000
#define D 128
#define NLAYERS 4
#define NODES_PER 2000

// ---------------- degree histogram ----------------
__global__ void count_deg_kernel(const int* __restrict__ src, const int* __restrict__ dst,
                                 int* __restrict__ cnt_out, int* __restrict__ cnt_in) {
    int e = blockIdx.x * 256 + threadIdx.x;
    if (e < N_EDGES) {
        atomicAdd(&cnt_out[src[e]], 1);
        atomicAdd(&cnt_in[dst[e]], 1);
    }
}

// ---------------- block-wise scan of cnt_in -> row_ptr (partial) ----------------
__global__ void scan1_kernel(const int* __restrict__ cnt, int* __restrict__ excl,
                             int* __restrict__ bsums) {
    __shared__ int s[256];
    int t = threadIdx.x;
    int i = blockIdx.x * 256 + t;
    int v = (i < N_NODES) ? cnt[i] : 0;
    s[t] = v;
    __syncthreads();
    for (int off = 1; off < 256; off <<= 1) {
        int u = (t >= off) ? s[t - off] : 0;
        __syncthreads();
        s[t] += u;
        __syncthreads();
    }
    if (i < N_NODES) excl[i] = s[t] - v;   // exclusive within block
    if (t == 255) bsums[blockIdx.x] = s[255];
}

__global__ void scan2_kernel(int* __restrict__ bsums, int nb) {
    __shared__ int s[256];
    int t = threadIdx.x;
    int v = (t < nb) ? bsums[t] : 0;
    s[t] = v;
    __syncthreads();
    for (int off = 1; off < 256; off <<= 1) {
        int u = (t >= off) ? s[t - off] : 0;
        __syncthreads();
        s[t] += u;
        __syncthreads();
    }
    if (t < nb) bsums[t] = s[t] - v;       // exclusive, in place
}

__global__ void finalize_kernel(const int* __restrict__ bsums, int* __restrict__ row_ptr,
                                int* __restrict__ cursor, const int* __restrict__ cnt_out,
                                const int* __restrict__ cnt_in, float* __restrict__ isq_src,
                                float* __restrict__ isq_dst) {
    int i = blockIdx.x * 256 + threadIdx.x;
    if (i < N_NODES) {
        int rp = row_ptr[i] + bsums[blockIdx.x];
        row_ptr[i] = rp;
        cursor[i] = rp;
        isq_src[i] = rsqrtf((float)max(cnt_out[i], 1));
        isq_dst[i] = rsqrtf((float)max(cnt_in[i], 1));
    }
    if (i == 0) row_ptr[N_NODES] = N_EDGES;
}

__global__ void fill_csr_kernel(const int* __restrict__ src, const int* __restrict__ dst,
                                int* __restrict__ cursor, int* __restrict__ csr_src) {
    int e = blockIdx.x * 256 + threadIdx.x;
    if (e < N_EDGES) {
        int pos = atomicAdd(&cursor[dst[e]], 1);
        csr_src[pos] = src[e];
    }
}

// ---------------- h = emb[labels] + positional encoding ----------------
// block b enumerates (g, i); node = g*2000 + perms[b]; table row i scattered to node.
__global__ void init_h_kernel(const int* __restrict__ labels, const int* __restrict__ perms,
                              const float* __restrict__ emb, float* __restrict__ h) {
    int b = blockIdx.x;
    int g = b / NODES_PER;
    int i = b - g * NODES_PER;
    int node = g * NODES_PER + perms[b];
    int d = threadIdx.x;
    int k = d >> 1;
    float ang = (float)(i + 1) * expf((float)(2 * k) * (-9.210340371976184f / 128.0f));
    float pe = (d & 1) ? cosf(ang) : sinf(ang);
    h[node * D + d] = emb[labels[node] * D + d] + pe;
}

// ---------------- m[v] = isq_dst[v] * sum_{e: dst=v} isq_src[s] * h[s] ----------------
__global__ void aggregate_kernel(const float* __restrict__ h, const int* __restrict__ row_ptr,
                                 const int* __restrict__ csr_src, const float* __restrict__ isq_src,
                                 const float* __restrict__ isq_dst, float* __restrict__ m) {
    int node = blockIdx.x * 2 + (threadIdx.x >> 7);
    int d = threadIdx.x & 127;
    int start = row_ptr[node], end = row_ptr[node + 1];
    float acc = 0.f;
    int e = start;
    for (; e + 4 <= end; e += 4) {
        int s0 = csr_src[e], s1 = csr_src[e + 1], s2 = csr_src[e + 2], s3 = csr_src[e + 3];
        float w0 = isq_src[s0], w1 = isq_src[s1], w2 = isq_src[s2], w3 = isq_src[s3];
        acc += w0 * h[s0 * D + d];
        acc += w1 * h[s1 * D + d];
        acc += w2 * h[s2 * D + d];
        acc += w3 * h[s3 * D + d];
    }
    for (; e < end; ++e) {
        int s = csr_src[e];
        acc += isq_src[s] * h[s * D + d];
    }
    m[node * D + d] = acc * isq_dst[node];
}

// ---------------- h = relu(m @ W + b) + h  (in place, per 128-row x 64-col tile) ----------------
__global__ __launch_bounds__(256) void layer_kernel(const float* __restrict__ m,
                                                    const float* __restrict__ W,
                                                    const float* __restrict__ bias,
                                                    float* __restrict__ h) {
    __shared__ float msT[128][132];   // [k][row], +4 pad keeps 16B alignment for b128 reads
    int t = threadIdx.x;
    int rowbase = blockIdx.x * 128;
    int colbase = blockIdx.y * 64;

    for (int i = t; i < 4096; i += 256) {
        int row = i >> 5;
        int kc = i & 31;
        int grow = rowbase + row;
        float4 v = (grow < N_NODES) ? *(const float4*)&m[grow * D + kc * 4]
                                    : make_float4(0.f, 0.f, 0.f, 0.f);
        msT[kc * 4 + 0][row] = v.x;
        msT[kc * 4 + 1][row] = v.y;
        msT[kc * 4 + 2][row] = v.z;
        msT[kc * 4 + 3][row] = v.w;
    }
    __syncthreads();

    int tx = t & 15, ty = t >> 4;
    int c0 = colbase + tx * 4;
    int r0 = ty * 8;
    float acc[8][4];
    float4 bv = *(const float4*)&bias[c0];
#pragma unroll
    for (int i = 0; i < 8; ++i) {
        acc[i][0] = bv.x; acc[i][1] = bv.y; acc[i][2] = bv.z; acc[i][3] = bv.w;
    }
#pragma unroll 4
    for (int k = 0; k < 128; ++k) {
        float4 wv = *(const float4*)&W[k * D + c0];
        const float4* mr = (const float4*)&msT[k][r0];
        float4 ma = mr[0], mb = mr[1];
        float mv[8] = {ma.x, ma.y, ma.z, ma.w, mb.x, mb.y, mb.z, mb.w};
#pragma unroll
        for (int i = 0; i < 8; ++i) {
            acc[i][0] += mv[i] * wv.x;
            acc[i][1] += mv[i] * wv.y;
            acc[i][2] += mv[i] * wv.z;
            acc[i][3] += mv[i] * wv.w;
        }
    }
#pragma unroll
    for (int i = 0; i < 8; ++i) {
        int row = rowbase + r0 + i;
        if (row < N_NODES) {
            float4 hv = *(const float4*)&h[row * D + c0];
            float4 o;
            o.x = fmaxf(acc[i][0], 0.f) + hv.x;
            o.y = fmaxf(acc[i][1], 0.f) + hv.y;
            o.z = fmaxf(acc[i][2], 0.f) + hv.z;
            o.w = fmaxf(acc[i][3], 0.f) + hv.w;
            *(float4*)&h[row * D + c0] = o;
        }
    }
}

// ---------------- fused MLP readout: 128 -> 64 -> 32 -> 128 ----------------
__global__ __launch_bounds__(256) void readout_kernel(const float* __restrict__ h,
        const float* __restrict__ w1, const float* __restrict__ b1,
        const float* __restrict__ w2, const float* __restrict__ b2,
        const float* __restrict__ w3, const float* __restrict__ b3,
        float* __restrict__ out) {
    __shared__ float w1s[128][64];
    __shared__ float w2s[64][32];
    __shared__ float w3s[32][128];
    __shared__ float b1s[64], b2s[32], b3s[128];
    __shared__ float hs[8][128];
    __shared__ float x1s[8][64];
    __shared__ float x2s[8][32];
    int t = threadIdx.x;
    for (int i = t; i < 8192; i += 256) w1s[i >> 6][i & 63] = w1[i];
    for (int i = t; i < 2048; i += 256) w2s[i >> 5][i & 31] = w2[i];
    for (int i = t; i < 4096; i += 256) w3s[i >> 7][i & 127] = w3[i];
    if (t < 64) b1s[t] = b1[t];
    if (t < 32) b2s[t] = b2[t];
    if (t < 128) b3s[t] = b3[t];
    __syncthreads();

    int base0 = blockIdx.x * 32;
    for (int rb = 0; rb < 4; ++rb) {
        int base = base0 + rb * 8;
        for (int i = t; i < 1024; i += 256) {
            int r = i >> 7, d = i & 127;
            int row = base + r;
            hs[r][d] = (row < N_NODES) ? h[row * D + d] : 0.f;
        }
        __syncthreads();
        {   // x1 = relu(h @ w1 + b1): 4 rows x 64 cols per pass
            int c = t & 63;
            int rr = t >> 6;
#pragma unroll
            for (int p = 0; p < 2; ++p) {
                int r = p * 4 + rr;
                float acc = b1s[c];
#pragma unroll 8
                for (int k = 0; k < 128; ++k) acc += hs[r][k] * w1s[k][c];
                x1s[r][c] = fmaxf(acc, 0.f);
            }
        }
        __syncthreads();
        {   // x2 = relu(x1 @ w2 + b2): 8 rows x 32 cols
            int c = t & 31, r = t >> 5;
            float acc = b2s[c];
#pragma unroll 8
            for (int k = 0; k < 64; ++k) acc += x1s[r][k] * w2s[k][c];
            x2s[r][c] = fmaxf(acc, 0.f);
        }
        __syncthreads();
        {   // out = x2 @ w3 + b3: 2 rows x 128 cols per pass
            int c = t & 127, rr = t >> 7;
#pragma unroll
            for (int p = 0; p < 4; ++p) {
                int r = p * 2 + rr;
                int row = base + r;
                if (row < N_NODES) {
                    float acc = b3s[c];
#pragma unroll 8
                    for (int k = 0; k < 32; ++k) acc += x2s[r][k] * w3s[k][c];
                    out[row * D + c] = acc;
                }
            }
        }
        __syncthreads();
    }
}

extern "C" void kernel_launch(void* const* d_in, const int* in_sizes, int n_in,
                              void* d_out, int out_size, void* d_ws, size_t ws_size,
                              hipStream_t stream) {
    const int*   labels = (const int*)d_in[0];
    const int*   src    = (const int*)d_in[1];
    const int*   dst    = (const int*)d_in[2];
    const int*   perms  = (const int*)d_in[3];
    const float* emb    = (const float*)d_in[4];
    const float* Ws     = (const float*)d_in[5];
    const float* bs     = (const float*)d_in[6];
    const float* w1     = (const float*)d_in[7];
    const float* b1     = (const float*)d_in[8];
    const float* w2     = (const float*)d_in[9];
    const float* b2     = (const float*)d_in[10];
    const float* w3     = (const float*)d_in[11];
    const float* b3     = (const float*)d_in[12];
    float* out = (float*)d_out;

    char* p = (char*)d_ws;
    auto alloc = [&](size_t bytes) -> char* {
        char* r = p;
        p += (bytes + 255) & ~size_t(255);
        return r;
    };
    float* h       = (float*)alloc((size_t)N_NODES * D * 4);
    float* m       = (float*)alloc((size_t)N_NODES * D * 4);
    float* isq_src = (float*)alloc((size_t)N_NODES * 4);
    float* isq_dst = (float*)alloc((size_t)N_NODES * 4);
    int*   cnt     = (int*)alloc((size_t)2 * N_NODES * 4);   // cnt_out | cnt_in
    int*   cnt_out = cnt;
    int*   cnt_in  = cnt + N_NODES;
    int*   row_ptr = (int*)alloc((size_t)(N_NODES + 1) * 4);
    int*   cursor  = (int*)alloc((size_t)N_NODES * 4);
    int*   csr_src = (int*)alloc((size_t)N_EDGES * 4);
    int*   bsums   = (int*)alloc(256 * 4);

    hipMemsetAsync(cnt, 0, (size_t)2 * N_NODES * 4, stream);
    count_deg_kernel<<<(N_EDGES + 255) / 256, 256, 0, stream>>>(src, dst, cnt_out, cnt_in);
    int nb = (N_NODES + 255) / 256;   // 196
    scan1_kernel<<<nb, 256, 0, stream>>>(cnt_in, row_ptr, bsums);
    scan2_kernel<<<1, 256, 0, stream>>>(bsums, nb);
    finalize_kernel<<<nb, 256, 0, stream>>>(bsums, row_ptr, cursor, cnt_out, cnt_in,
                                            isq_src, isq_dst);
    fill_csr_kernel<<<(N_EDGES + 255) / 256, 256, 0, stream>>>(src, dst, cursor, csr_src);
    init_h_kernel<<<N_NODES, 128, 0, stream>>>(labels, perms, emb, h);

    for (int l = 0; l < NLAYERS; ++l) {
        aggregate_kernel<<<N_NODES / 2, 256, 0, stream>>>(h, row_ptr, csr_src,
                                                          isq_src, isq_dst, m);
        dim3 g((N_NODES + 127) / 128, 2);
        layer_kernel<<<g, 256, 0, stream>>>(m, Ws + (size_t)l * D * D, bs + (size_t)l * D, h);
    }
    readout_kernel<<<(N_NODES + 31) / 32, 256, 0, stream>>>(h, w1, b1, w2, b2, w3, b3, out);
}

// Round 2
// 720.669 us; speedup vs baseline: 1.1301x; 1.1301x over previous
//
#include <hip/hip_runtime.h>

#define N_NODES 50000
#define N_EDGES 800000
#define D 128
#define NLAYERS 4
#define NODES_PER 2000

// ---------------- degree histogram ----------------
__global__ void count_deg_kernel(const int* __restrict__ src, const int* __restrict__ dst,
                                 int* __restrict__ cnt_out, int* __restrict__ cnt_in) {
    int e = blockIdx.x * 256 + threadIdx.x;
    if (e < N_EDGES) {
        atomicAdd(&cnt_out[src[e]], 1);
        atomicAdd(&cnt_in[dst[e]], 1);
    }
}

// ---------------- block-wise scan of cnt_in -> row_ptr (partial) ----------------
__global__ void scan1_kernel(const int* __restrict__ cnt, int* __restrict__ excl,
                             int* __restrict__ bsums) {
    __shared__ int s[256];
    int t = threadIdx.x;
    int i = blockIdx.x * 256 + t;
    int v = (i < N_NODES) ? cnt[i] : 0;
    s[t] = v;
    __syncthreads();
    for (int off = 1; off < 256; off <<= 1) {
        int u = (t >= off) ? s[t - off] : 0;
        __syncthreads();
        s[t] += u;
        __syncthreads();
    }
    if (i < N_NODES) excl[i] = s[t] - v;   // exclusive within block
    if (t == 255) bsums[blockIdx.x] = s[255];
}

__global__ void scan2_kernel(int* __restrict__ bsums, int nb) {
    __shared__ int s[256];
    int t = threadIdx.x;
    int v = (t < nb) ? bsums[t] : 0;
    s[t] = v;
    __syncthreads();
    for (int off = 1; off < 256; off <<= 1) {
        int u = (t >= off) ? s[t - off] : 0;
        __syncthreads();
        s[t] += u;
        __syncthreads();
    }
    if (t < nb) bsums[t] = s[t] - v;       // exclusive, in place
}

__global__ void finalize_kernel(const int* __restrict__ bsums, int* __restrict__ row_ptr,
                                int* __restrict__ cursor, const int* __restrict__ cnt_out,
                                const int* __restrict__ cnt_in, float* __restrict__ isq_src,
                                float* __restrict__ isq_dst) {
    int i = blockIdx.x * 256 + threadIdx.x;
    if (i < N_NODES) {
        int rp = row_ptr[i] + bsums[blockIdx.x];
        row_ptr[i] = rp;
        cursor[i] = rp;
        isq_src[i] = rsqrtf((float)max(cnt_out[i], 1));
        isq_dst[i] = rsqrtf((float)max(cnt_in[i], 1));
    }
    if (i == 0) row_ptr[N_NODES] = N_EDGES;
}

__global__ void fill_csr_kernel(const int* __restrict__ src, const int* __restrict__ dst,
                                int* __restrict__ cursor, int* __restrict__ csr_src) {
    int e = blockIdx.x * 256 + threadIdx.x;
    if (e < N_EDGES) {
        int pos = atomicAdd(&cursor[dst[e]], 1);
        csr_src[pos] = src[e];
    }
}

// ---------------- h = emb[labels] + positional encoding ----------------
__global__ void init_h_kernel(const int* __restrict__ labels, const int* __restrict__ perms,
                              const float* __restrict__ emb, float* __restrict__ h) {
    int b = blockIdx.x;
    int g = b / NODES_PER;
    int i = b - g * NODES_PER;
    int node = g * NODES_PER + perms[b];
    int d = threadIdx.x;
    int k = d >> 1;
    float ang = (float)(i + 1) * expf((float)(2 * k) * (-9.210340371976184f / 128.0f));
    float pe = (d & 1) ? cosf(ang) : sinf(ang);
    h[node * D + d] = emb[labels[node] * D + d] + pe;
}

// ---------------- m[v] = isq_dst[v] * sum_{e: dst=v} isq_src[s] * h[s] ----------------
// one 64-lane wave per node, float2 per lane (128 features)
__global__ __launch_bounds__(256) void aggregate_kernel(const float* __restrict__ h,
        const int* __restrict__ row_ptr, const int* __restrict__ csr_src,
        const float* __restrict__ isq_src, const float* __restrict__ isq_dst,
        float* __restrict__ m) {
    int node = blockIdx.x * 4 + (threadIdx.x >> 6);
    int lane = threadIdx.x & 63;
    int start = row_ptr[node], end = row_ptr[node + 1];
    const float* hb = h + lane * 2;
    float ax = 0.f, ay = 0.f;
    int e = start;
    for (; e + 4 <= end; e += 4) {
        int s0 = csr_src[e], s1 = csr_src[e + 1], s2 = csr_src[e + 2], s3 = csr_src[e + 3];
        float w0 = isq_src[s0], w1 = isq_src[s1], w2 = isq_src[s2], w3 = isq_src[s3];
        float2 v0 = *(const float2*)&hb[s0 * D];
        float2 v1 = *(const float2*)&hb[s1 * D];
        float2 v2 = *(const float2*)&hb[s2 * D];
        float2 v3 = *(const float2*)&hb[s3 * D];
        ax += w0 * v0.x; ay += w0 * v0.y;
        ax += w1 * v1.x; ay += w1 * v1.y;
        ax += w2 * v2.x; ay += w2 * v2.y;
        ax += w3 * v3.x; ay += w3 * v3.y;
    }
    for (; e < end; ++e) {
        int s = csr_src[e];
        float w = isq_src[s];
        float2 v = *(const float2*)&hb[s * D];
        ax += w * v.x; ay += w * v.y;
    }
    float wd = isq_dst[node];
    *(float2*)&m[node * D + lane * 2] = make_float2(ax * wd, ay * wd);
}

// ---------------- h = relu(m @ W + b) + h : 128-row x 128-col tile, 8x8/thread ----------------
__global__ __launch_bounds__(256) void layer_kernel(const float* __restrict__ m,
                                                    const float* __restrict__ W,
                                                    const float* __restrict__ bias,
                                                    float* __restrict__ h) {
    __shared__ float msT[128][132];   // [k][row]
    int t = threadIdx.x;
    int rowbase = blockIdx.x * 128;

    for (int i = t; i < 4096; i += 256) {
        int row = i >> 5;
        int kc = i & 31;
        int grow = rowbase + row;
        float4 v = (grow < N_NODES) ? *(const float4*)&m[grow * D + kc * 4]
                                    : make_float4(0.f, 0.f, 0.f, 0.f);
        msT[kc * 4 + 0][row] = v.x;
        msT[kc * 4 + 1][row] = v.y;
        msT[kc * 4 + 2][row] = v.z;
        msT[kc * 4 + 3][row] = v.w;
    }
    __syncthreads();

    int tx = t & 15, ty = t >> 4;
    int c0 = tx * 8;
    int r0 = ty * 8;
    float acc[8][8];
    float4 bv0 = *(const float4*)&bias[c0];
    float4 bv1 = *(const float4*)&bias[c0 + 4];
#pragma unroll
    for (int i = 0; i < 8; ++i) {
        acc[i][0] = bv0.x; acc[i][1] = bv0.y; acc[i][2] = bv0.z; acc[i][3] = bv0.w;
        acc[i][4] = bv1.x; acc[i][5] = bv1.y; acc[i][6] = bv1.z; acc[i][7] = bv1.w;
    }
#pragma unroll 2
    for (int k = 0; k < 128; ++k) {
        float4 wa = *(const float4*)&W[k * D + c0];
        float4 wb = *(const float4*)&W[k * D + c0 + 4];
        float4 ma = *(const float4*)&msT[k][r0];
        float4 mb = *(const float4*)&msT[k][r0 + 4];
        float mv[8] = {ma.x, ma.y, ma.z, ma.w, mb.x, mb.y, mb.z, mb.w};
        float wv[8] = {wa.x, wa.y, wa.z, wa.w, wb.x, wb.y, wb.z, wb.w};
#pragma unroll
        for (int i = 0; i < 8; ++i)
#pragma unroll
            for (int j = 0; j < 8; ++j)
                acc[i][j] += mv[i] * wv[j];
    }
#pragma unroll
    for (int i = 0; i < 8; ++i) {
        int row = rowbase + r0 + i;
        if (row < N_NODES) {
            float4 h0 = *(const float4*)&h[row * D + c0];
            float4 h1 = *(const float4*)&h[row * D + c0 + 4];
            float4 o0, o1;
            o0.x = fmaxf(acc[i][0], 0.f) + h0.x;
            o0.y = fmaxf(acc[i][1], 0.f) + h0.y;
            o0.z = fmaxf(acc[i][2], 0.f) + h0.z;
            o0.w = fmaxf(acc[i][3], 0.f) + h0.w;
            o1.x = fmaxf(acc[i][4], 0.f) + h1.x;
            o1.y = fmaxf(acc[i][5], 0.f) + h1.y;
            o1.z = fmaxf(acc[i][6], 0.f) + h1.z;
            o1.w = fmaxf(acc[i][7], 0.f) + h1.w;
            *(float4*)&h[row * D + c0] = o0;
            *(float4*)&h[row * D + c0 + 4] = o1;
        }
    }
}

// ---------------- fused MLP readout: thread-per-row, uniform (scalar) weight loads ----------
__global__ __launch_bounds__(128) void readout_kernel(const float* __restrict__ h,
        const float* __restrict__ w1, const float* __restrict__ b1,
        const float* __restrict__ w2, const float* __restrict__ b2,
        const float* __restrict__ w3, const float* __restrict__ b3,
        float* __restrict__ out) {
    __shared__ float hsT[32][129];    // [k-within-chunk][row]; reused as out transpose buf
    int t = threadIdx.x;
    int base = blockIdx.x * 128;

    float y1[64];
#pragma unroll
    for (int c = 0; c < 64; ++c) y1[c] = b1[c];

    for (int kc = 0; kc < 4; ++kc) {
        __syncthreads();
        for (int i = t; i < 1024; i += 128) {
            int r = i >> 3, k4 = i & 7;
            int gr = min(base + r, N_NODES - 1);
            float4 v = *(const float4*)&h[gr * D + kc * 32 + k4 * 4];
            hsT[k4 * 4 + 0][r] = v.x;
            hsT[k4 * 4 + 1][r] = v.y;
            hsT[k4 * 4 + 2][r] = v.z;
            hsT[k4 * 4 + 3][r] = v.w;
        }
        __syncthreads();
        for (int k = 0; k < 32; ++k) {
            float hv = hsT[k][t];
            const float* wr = w1 + (kc * 32 + k) * 64;
#pragma unroll
            for (int c = 0; c < 64; ++c) y1[c] = fmaf(hv, wr[c], y1[c]);
        }
    }
#pragma unroll
    for (int c = 0; c < 64; ++c) y1[c] = fmaxf(y1[c], 0.f);

    float y2[32];
#pragma unroll
    for (int j = 0; j < 32; ++j) y2[j] = b2[j];
#pragma unroll
    for (int k = 0; k < 64; ++k) {
        const float* wr = w2 + k * 32;
#pragma unroll
        for (int j = 0; j < 32; ++j) y2[j] = fmaf(y1[k], wr[j], y2[j]);
    }
#pragma unroll
    for (int j = 0; j < 32; ++j) y2[j] = fmaxf(y2[j], 0.f);

    for (int cc = 0; cc < 4; ++cc) {
        float o[32];
#pragma unroll
        for (int i = 0; i < 32; ++i) o[i] = b3[cc * 32 + i];
#pragma unroll
        for (int j = 0; j < 32; ++j) {
            const float* wr = w3 + j * D + cc * 32;
#pragma unroll
            for (int i = 0; i < 32; ++i) o[i] = fmaf(y2[j], wr[i], o[i]);
        }
        __syncthreads();
#pragma unroll
        for (int i = 0; i < 32; ++i) hsT[i][t] = o[i];
        __syncthreads();
        for (int i = t; i < 1024; i += 128) {
            int r = i >> 3, k4 = i & 7;
            if (base + r < N_NODES) {
                float4 v = make_float4(hsT[k4 * 4 + 0][r], hsT[k4 * 4 + 1][r],
                                       hsT[k4 * 4 + 2][r], hsT[k4 * 4 + 3][r]);
                *(float4*)&out[(base + r) * D + cc * 32 + k4 * 4] = v;
            }
        }
    }
}

extern "C" void kernel_launch(void* const* d_in, const int* in_sizes, int n_in,
                              void* d_out, int out_size, void* d_ws, size_t ws_size,
                              hipStream_t stream) {
    const int*   labels = (const int*)d_in[0];
    const int*   src    = (const int*)d_in[1];
    const int*   dst    = (const int*)d_in[2];
    const int*   perms  = (const int*)d_in[3];
    const float* emb    = (const float*)d_in[4];
    const float* Ws     = (const float*)d_in[5];
    const float* bs     = (const float*)d_in[6];
    const float* w1     = (const float*)d_in[7];
    const float* b1     = (const float*)d_in[8];
    const float* w2     = (const float*)d_in[9];
    const float* b2     = (const float*)d_in[10];
    const float* w3     = (const float*)d_in[11];
    const float* b3     = (const float*)d_in[12];
    float* out = (float*)d_out;

    char* p = (char*)d_ws;
    auto alloc = [&](size_t bytes) -> char* {
        char* r = p;
        p += (bytes + 255) & ~size_t(255);
        return r;
    };
    float* h       = (float*)alloc((size_t)N_NODES * D * 4);
    float* m       = (float*)alloc((size_t)N_NODES * D * 4);
    float* isq_src = (float*)alloc((size_t)N_NODES * 4);
    float* isq_dst = (float*)alloc((size_t)N_NODES * 4);
    int*   cnt     = (int*)alloc((size_t)2 * N_NODES * 4);
    int*   cnt_out = cnt;
    int*   cnt_in  = cnt + N_NODES;
    int*   row_ptr = (int*)alloc((size_t)(N_NODES + 1) * 4);
    int*   cursor  = (int*)alloc((size_t)N_NODES * 4);
    int*   csr_src = (int*)alloc((size_t)N_EDGES * 4);
    int*   bsums   = (int*)alloc(256 * 4);

    hipMemsetAsync(cnt, 0, (size_t)2 * N_NODES * 4, stream);
    count_deg_kernel<<<(N_EDGES + 255) / 256, 256, 0, stream>>>(src, dst, cnt_out, cnt_in);
    int nb = (N_NODES + 255) / 256;   // 196
    scan1_kernel<<<nb, 256, 0, stream>>>(cnt_in, row_ptr, bsums);
    scan2_kernel<<<1, 256, 0, stream>>>(bsums, nb);
    finalize_kernel<<<nb, 256, 0, stream>>>(bsums, row_ptr, cursor, cnt_out, cnt_in,
                                            isq_src, isq_dst);
    fill_csr_kernel<<<(N_EDGES + 255) / 256, 256, 0, stream>>>(src, dst, cursor, csr_src);
    init_h_kernel<<<N_NODES, 128, 0, stream>>>(labels, perms, emb, h);

    for (int l = 0; l < NLAYERS; ++l) {
        aggregate_kernel<<<N_NODES / 4, 256, 0, stream>>>(h, row_ptr, csr_src,
                                                          isq_src, isq_dst, m);
        layer_kernel<<<(N_NODES + 127) / 128, 256, 0, stream>>>(
            m, Ws + (size_t)l * D * D, bs + (size_t)l * D, h);
    }
    readout_kernel<<<(N_NODES + 127) / 128, 128, 0, stream>>>(h, w1, b1, w2, b2, w3, b3, out);
}

// Round 3
// 685.583 us; speedup vs baseline: 1.1879x; 1.0512x over previous
//
#include <hip/hip_runtime.h>

#define N_NODES 50000
#define N_EDGES 800000
#define D 128
#define NLAYERS 4
#define NODES_PER 2000

// ---------------- degree histogram ----------------
__global__ void count_deg_kernel(const int* __restrict__ src, const int* __restrict__ dst,
                                 int* __restrict__ cnt_out, int* __restrict__ cnt_in) {
    int e = blockIdx.x * 256 + threadIdx.x;
    if (e < N_EDGES) {
        atomicAdd(&cnt_out[src[e]], 1);
        atomicAdd(&cnt_in[dst[e]], 1);
    }
}

__global__ void scan1_kernel(const int* __restrict__ cnt, int* __restrict__ excl,
                             int* __restrict__ bsums) {
    __shared__ int s[256];
    int t = threadIdx.x;
    int i = blockIdx.x * 256 + t;
    int v = (i < N_NODES) ? cnt[i] : 0;
    s[t] = v;
    __syncthreads();
    for (int off = 1; off < 256; off <<= 1) {
        int u = (t >= off) ? s[t - off] : 0;
        __syncthreads();
        s[t] += u;
        __syncthreads();
    }
    if (i < N_NODES) excl[i] = s[t] - v;
    if (t == 255) bsums[blockIdx.x] = s[255];
}

__global__ void scan2_kernel(int* __restrict__ bsums, int nb) {
    __shared__ int s[256];
    int t = threadIdx.x;
    int v = (t < nb) ? bsums[t] : 0;
    s[t] = v;
    __syncthreads();
    for (int off = 1; off < 256; off <<= 1) {
        int u = (t >= off) ? s[t - off] : 0;
        __syncthreads();
        s[t] += u;
        __syncthreads();
    }
    if (t < nb) bsums[t] = s[t] - v;
}

__global__ void finalize_kernel(const int* __restrict__ bsums, int* __restrict__ row_ptr,
                                int* __restrict__ cursor, const int* __restrict__ cnt_out,
                                const int* __restrict__ cnt_in, float* __restrict__ isq_src,
                                float* __restrict__ isq_dst) {
    int i = blockIdx.x * 256 + threadIdx.x;
    if (i < N_NODES) {
        int rp = row_ptr[i] + bsums[blockIdx.x];
        row_ptr[i] = rp;
        cursor[i] = rp;
        isq_src[i] = rsqrtf((float)max(cnt_out[i], 1));
        isq_dst[i] = rsqrtf((float)max(cnt_in[i], 1));
    }
    if (i == 0) row_ptr[N_NODES] = N_EDGES;
}

__global__ void fill_csr_kernel(const int* __restrict__ src, const int* __restrict__ dst,
                                int* __restrict__ cursor, int* __restrict__ csr_src) {
    int e = blockIdx.x * 256 + threadIdx.x;
    if (e < N_EDGES) {
        int pos = atomicAdd(&cursor[dst[e]], 1);
        csr_src[pos] = src[e];
    }
}

// ---------------- h = emb[labels] + positional encoding ----------------
__global__ void init_h_kernel(const int* __restrict__ labels, const int* __restrict__ perms,
                              const float* __restrict__ emb, float* __restrict__ h) {
    int b = blockIdx.x;
    int g = b / NODES_PER;
    int i = b - g * NODES_PER;
    int node = g * NODES_PER + perms[b];
    int d = threadIdx.x;
    int k = d >> 1;
    float ang = (float)(i + 1) * expf((float)(2 * k) * (-9.210340371976184f / 128.0f));
    float pe = (d & 1) ? cosf(ang) : sinf(ang);
    h[node * D + d] = emb[labels[node] * D + d] + pe;
}

// ---------------- m[v] = isq_dst[v] * sum_{e: dst=v} isq_src[s] * h[s] ----------------
// one 64-lane wave per node, float2 per lane; unroll 8 for memory-level parallelism
__global__ __launch_bounds__(256) void aggregate_kernel(const float* __restrict__ h,
        const int* __restrict__ row_ptr, const int* __restrict__ csr_src,
        const float* __restrict__ isq_src, const float* __restrict__ isq_dst,
        float* __restrict__ m) {
    int node = blockIdx.x * 4 + (threadIdx.x >> 6);
    int lane = threadIdx.x & 63;
    int start = row_ptr[node], end = row_ptr[node + 1];
    const float* hb = h + lane * 2;
    float ax = 0.f, ay = 0.f;
    int e = start;
    for (; e + 8 <= end; e += 8) {
        int s0 = csr_src[e + 0], s1 = csr_src[e + 1], s2 = csr_src[e + 2], s3 = csr_src[e + 3];
        int s4 = csr_src[e + 4], s5 = csr_src[e + 5], s6 = csr_src[e + 6], s7 = csr_src[e + 7];
        float w0 = isq_src[s0], w1 = isq_src[s1], w2 = isq_src[s2], w3 = isq_src[s3];
        float w4 = isq_src[s4], w5 = isq_src[s5], w6 = isq_src[s6], w7 = isq_src[s7];
        float2 v0 = *(const float2*)&hb[s0 * D];
        float2 v1 = *(const float2*)&hb[s1 * D];
        float2 v2 = *(const float2*)&hb[s2 * D];
        float2 v3 = *(const float2*)&hb[s3 * D];
        float2 v4 = *(const float2*)&hb[s4 * D];
        float2 v5 = *(const float2*)&hb[s5 * D];
        float2 v6 = *(const float2*)&hb[s6 * D];
        float2 v7 = *(const float2*)&hb[s7 * D];
        ax += w0 * v0.x; ay += w0 * v0.y;
        ax += w1 * v1.x; ay += w1 * v1.y;
        ax += w2 * v2.x; ay += w2 * v2.y;
        ax += w3 * v3.x; ay += w3 * v3.y;
        ax += w4 * v4.x; ay += w4 * v4.y;
        ax += w5 * v5.x; ay += w5 * v5.y;
        ax += w6 * v6.x; ay += w6 * v6.y;
        ax += w7 * v7.x; ay += w7 * v7.y;
    }
    for (; e < end; ++e) {
        int s = csr_src[e];
        float w = isq_src[s];
        float2 v = *(const float2*)&hb[s * D];
        ax += w * v.x; ay += w * v.y;
    }
    float wd = isq_dst[node];
    *(float2*)&m[node * D + lane * 2] = make_float2(ax * wd, ay * wd);
}

// ---------------- h = relu(m @ W + b) + h : 128x128 tile, 8x8/thread, swizzled msT -------
// swizzle: value for (k,row) stored at msT[k][row ^ (((k>>2)&7)<<2)]
//  - staging writes: 4-way bank conflict (was 32-way with linear layout)
//  - k-loop b128 reads: conflict-free, still 16B aligned (XOR touches bits 2-4 only)
__global__ __launch_bounds__(256) void layer_kernel(const float* __restrict__ m,
                                                    const float* __restrict__ W,
                                                    const float* __restrict__ bias,
                                                    float* __restrict__ h) {
    __shared__ float msT[128][132];
    int t = threadIdx.x;
    int rowbase = blockIdx.x * 128;

    for (int i = t; i < 4096; i += 256) {
        int row = i >> 5;
        int kc = i & 31;
        int grow = rowbase + row;
        float4 v = (grow < N_NODES) ? *(const float4*)&m[grow * D + kc * 4]
                                    : make_float4(0.f, 0.f, 0.f, 0.f);
        int cs = row ^ ((kc & 7) << 2);   // (k>>2)&7 == kc&7 for k in [4kc,4kc+3]
        msT[kc * 4 + 0][cs] = v.x;
        msT[kc * 4 + 1][cs] = v.y;
        msT[kc * 4 + 2][cs] = v.z;
        msT[kc * 4 + 3][cs] = v.w;
    }
    __syncthreads();

    int tx = t & 15, ty = t >> 4;
    int c0 = tx * 8;
    int r0 = ty * 8;
    float acc[8][8];
    float4 bv0 = *(const float4*)&bias[c0];
    float4 bv1 = *(const float4*)&bias[c0 + 4];
#pragma unroll
    for (int i = 0; i < 8; ++i) {
        acc[i][0] = bv0.x; acc[i][1] = bv0.y; acc[i][2] = bv0.z; acc[i][3] = bv0.w;
        acc[i][4] = bv1.x; acc[i][5] = bv1.y; acc[i][6] = bv1.z; acc[i][7] = bv1.w;
    }
#pragma unroll 4
    for (int k = 0; k < 128; ++k) {
        int s4 = ((k >> 2) & 7) << 2;
        float4 wa = *(const float4*)&W[k * D + c0];
        float4 wb = *(const float4*)&W[k * D + c0 + 4];
        float4 ma = *(const float4*)&msT[k][r0 ^ s4];
        float4 mb = *(const float4*)&msT[k][(r0 + 4) ^ s4];
        float mv[8] = {ma.x, ma.y, ma.z, ma.w, mb.x, mb.y, mb.z, mb.w};
        float wv[8] = {wa.x, wa.y, wa.z, wa.w, wb.x, wb.y, wb.z, wb.w};
#pragma unroll
        for (int i = 0; i < 8; ++i)
#pragma unroll
            for (int j = 0; j < 8; ++j)
                acc[i][j] += mv[i] * wv[j];
    }
#pragma unroll
    for (int i = 0; i < 8; ++i) {
        int row = rowbase + r0 + i;
        if (row < N_NODES) {
            float4 h0 = *(const float4*)&h[row * D + c0];
            float4 h1 = *(const float4*)&h[row * D + c0 + 4];
            float4 o0, o1;
            o0.x = fmaxf(acc[i][0], 0.f) + h0.x;
            o0.y = fmaxf(acc[i][1], 0.f) + h0.y;
            o0.z = fmaxf(acc[i][2], 0.f) + h0.z;
            o0.w = fmaxf(acc[i][3], 0.f) + h0.w;
            o1.x = fmaxf(acc[i][4], 0.f) + h1.x;
            o1.y = fmaxf(acc[i][5], 0.f) + h1.y;
            o1.z = fmaxf(acc[i][6], 0.f) + h1.z;
            o1.w = fmaxf(acc[i][7], 0.f) + h1.w;
            *(float4*)&h[row * D + c0] = o0;
            *(float4*)&h[row * D + c0 + 4] = o1;
        }
    }
}

// ---------------- layer 4 + fused MLP readout ----------------
// 64-row tile, 256 threads (thread tile 4 rows x {8,4,2,8} cols per stage).
// LDS: lds0 = msT (m^T) -> reused as hT (h_new^T) -> first 32 rows reused as y2T.
//      y1T separate. Total 52 KiB -> 3 blocks/CU.
__global__ __launch_bounds__(256) void layer4_readout_kernel(const float* __restrict__ m,
        const float* __restrict__ W, const float* __restrict__ bias,
        const float* __restrict__ h,
        const float* __restrict__ w1, const float* __restrict__ b1,
        const float* __restrict__ w2, const float* __restrict__ b2,
        const float* __restrict__ w3, const float* __restrict__ b3,
        float* __restrict__ out) {
    __shared__ float lds0[128][68];   // msT / hT / y2T(first 32 rows)
    __shared__ float y1T[64][68];
    int t = threadIdx.x;
    int rowbase = blockIdx.x * 64;
    int tx = t & 15, ty = t >> 4;
    int r0 = ty * 4;

    // ---- stage m^T (swizzled) ----
    for (int i = t; i < 2048; i += 256) {
        int row = i >> 5;
        int kc = i & 31;
        int grow = rowbase + row;
        float4 v = (grow < N_NODES) ? *(const float4*)&m[grow * D + kc * 4]
                                    : make_float4(0.f, 0.f, 0.f, 0.f);
        int cs = row ^ ((kc & 7) << 2);
        lds0[kc * 4 + 0][cs] = v.x;
        lds0[kc * 4 + 1][cs] = v.y;
        lds0[kc * 4 + 2][cs] = v.z;
        lds0[kc * 4 + 3][cs] = v.w;
    }
    __syncthreads();

    // ---- stage0: acc = m @ W  (4 rows x 8 cols / thread) ----
    {
        int c0 = tx * 8;
        float acc[4][8];
        float4 bv0 = *(const float4*)&bias[c0];
        float4 bv1 = *(const float4*)&bias[c0 + 4];
#pragma unroll
        for (int i = 0; i < 4; ++i) {
            acc[i][0] = bv0.x; acc[i][1] = bv0.y; acc[i][2] = bv0.z; acc[i][3] = bv0.w;
            acc[i][4] = bv1.x; acc[i][5] = bv1.y; acc[i][6] = bv1.z; acc[i][7] = bv1.w;
        }
#pragma unroll 4
        for (int k = 0; k < 128; ++k) {
            int s4 = ((k >> 2) & 7) << 2;
            float4 wa = *(const float4*)&W[k * D + c0];
            float4 wb = *(const float4*)&W[k * D + c0 + 4];
            float4 ma = *(const float4*)&lds0[k][r0 ^ s4];
            float mv[4] = {ma.x, ma.y, ma.z, ma.w};
            float wv[8] = {wa.x, wa.y, wa.z, wa.w, wb.x, wb.y, wb.z, wb.w};
#pragma unroll
            for (int i = 0; i < 4; ++i)
#pragma unroll
                for (int j = 0; j < 8; ++j)
                    acc[i][j] += mv[i] * wv[j];
        }
        // residual
        float hn[4][8];
#pragma unroll
        for (int i = 0; i < 4; ++i) {
            int row = rowbase + r0 + i;
            if (row < N_NODES) {
                float4 h0 = *(const float4*)&h[row * D + c0];
                float4 h1 = *(const float4*)&h[row * D + c0 + 4];
                hn[i][0] = fmaxf(acc[i][0], 0.f) + h0.x;
                hn[i][1] = fmaxf(acc[i][1], 0.f) + h0.y;
                hn[i][2] = fmaxf(acc[i][2], 0.f) + h0.z;
                hn[i][3] = fmaxf(acc[i][3], 0.f) + h0.w;
                hn[i][4] = fmaxf(acc[i][4], 0.f) + h1.x;
                hn[i][5] = fmaxf(acc[i][5], 0.f) + h1.y;
                hn[i][6] = fmaxf(acc[i][6], 0.f) + h1.z;
                hn[i][7] = fmaxf(acc[i][7], 0.f) + h1.w;
            } else {
#pragma unroll
                for (int j = 0; j < 8; ++j) hn[i][j] = 0.f;
            }
        }
        __syncthreads();   // all msT reads done; lds0 becomes hT
        // write h_new^T as b128 (4 rows packed), swizzled
#pragma unroll
        for (int j = 0; j < 8; ++j) {
            int c = c0 + j;
            int cs = r0 ^ (((c >> 2) & 7) << 2);
            float4 v = make_float4(hn[0][j], hn[1][j], hn[2][j], hn[3][j]);
            *(float4*)&lds0[c][cs] = v;
        }
    }
    __syncthreads();

    // ---- stage1: y1 = relu(h_new @ w1 + b1)  (4 rows x 4 cols / thread) ----
    {
        int c1 = tx * 4;
        float acc[4][4];
        float4 bv = *(const float4*)&b1[c1];
#pragma unroll
        for (int i = 0; i < 4; ++i) {
            acc[i][0] = bv.x; acc[i][1] = bv.y; acc[i][2] = bv.z; acc[i][3] = bv.w;
        }
#pragma unroll 4
        for (int k = 0; k < 128; ++k) {
            int s4 = ((k >> 2) & 7) << 2;
            float4 wa = *(const float4*)&w1[k * 64 + c1];
            float4 ma = *(const float4*)&lds0[k][r0 ^ s4];
            float mv[4] = {ma.x, ma.y, ma.z, ma.w};
            float wv[4] = {wa.x, wa.y, wa.z, wa.w};
#pragma unroll
            for (int i = 0; i < 4; ++i)
#pragma unroll
                for (int j = 0; j < 4; ++j)
                    acc[i][j] += mv[i] * wv[j];
        }
#pragma unroll
        for (int j = 0; j < 4; ++j) {
            int c = c1 + j;
            int cs = r0 ^ (((c >> 2) & 7) << 2);
            float4 v = make_float4(fmaxf(acc[0][j], 0.f), fmaxf(acc[1][j], 0.f),
                                   fmaxf(acc[2][j], 0.f), fmaxf(acc[3][j], 0.f));
            *(float4*)&y1T[c][cs] = v;
        }
    }
    __syncthreads();

    // ---- stage2: y2 = relu(y1 @ w2 + b2)  (4 rows x 2 cols / thread) ----
    float (*y2T)[68] = (float(*)[68])lds0;
    {
        int c2 = tx * 2;
        float acc[4][2];
        float2 bv = *(const float2*)&b2[c2];
#pragma unroll
        for (int i = 0; i < 4; ++i) { acc[i][0] = bv.x; acc[i][1] = bv.y; }
#pragma unroll 4
        for (int k = 0; k < 64; ++k) {
            int s4 = ((k >> 2) & 7) << 2;
            float2 wa = *(const float2*)&w2[k * 32 + c2];
            float4 ma = *(const float4*)&y1T[k][r0 ^ s4];
            float mv[4] = {ma.x, ma.y, ma.z, ma.w};
#pragma unroll
            for (int i = 0; i < 4; ++i) {
                acc[i][0] += mv[i] * wa.x;
                acc[i][1] += mv[i] * wa.y;
            }
        }
#pragma unroll
        for (int j = 0; j < 2; ++j) {
            int c = c2 + j;
            int cs = r0 ^ (((c >> 2) & 7) << 2);
            float4 v = make_float4(fmaxf(acc[0][j], 0.f), fmaxf(acc[1][j], 0.f),
                                   fmaxf(acc[2][j], 0.f), fmaxf(acc[3][j], 0.f));
            *(float4*)&y2T[c][cs] = v;
        }
    }
    __syncthreads();

    // ---- stage3: out = y2 @ w3 + b3  (4 rows x 8 cols / thread) ----
    {
        int c0 = tx * 8;
        float acc[4][8];
        float4 bv0 = *(const float4*)&b3[c0];
        float4 bv1 = *(const float4*)&b3[c0 + 4];
#pragma unroll
        for (int i = 0; i < 4; ++i) {
            acc[i][0] = bv0.x; acc[i][1] = bv0.y; acc[i][2] = bv0.z; acc[i][3] = bv0.w;
            acc[i][4] = bv1.x; acc[i][5] = bv1.y; acc[i][6] = bv1.z; acc[i][7] = bv1.w;
        }
#pragma unroll
        for (int k = 0; k < 32; ++k) {
            int s4 = ((k >> 2) & 7) << 2;
            float4 wa = *(const float4*)&w3[k * D + c0];
            float4 wb = *(const float4*)&w3[k * D + c0 + 4];
            float4 ma = *(const float4*)&y2T[k][r0 ^ s4];
            float mv[4] = {ma.x, ma.y, ma.z, ma.w};
            float wv[8] = {wa.x, wa.y, wa.z, wa.w, wb.x, wb.y, wb.z, wb.w};
#pragma unroll
            for (int i = 0; i < 4; ++i)
#pragma unroll
                for (int j = 0; j < 8; ++j)
                    acc[i][j] += mv[i] * wv[j];
        }
#pragma unroll
        for (int i = 0; i < 4; ++i) {
            int row = rowbase + r0 + i;
            if (row < N_NODES) {
                *(float4*)&out[row * D + c0] = make_float4(acc[i][0], acc[i][1], acc[i][2], acc[i][3]);
                *(float4*)&out[row * D + c0 + 4] = make_float4(acc[i][4], acc[i][5], acc[i][6], acc[i][7]);
            }
        }
    }
}

extern "C" void kernel_launch(void* const* d_in, const int* in_sizes, int n_in,
                              void* d_out, int out_size, void* d_ws, size_t ws_size,
                              hipStream_t stream) {
    const int*   labels = (const int*)d_in[0];
    const int*   src    = (const int*)d_in[1];
    const int*   dst    = (const int*)d_in[2];
    const int*   perms  = (const int*)d_in[3];
    const float* emb    = (const float*)d_in[4];
    const float* Ws     = (const float*)d_in[5];
    const float* bs     = (const float*)d_in[6];
    const float* w1     = (const float*)d_in[7];
    const float* b1     = (const float*)d_in[8];
    const float* w2     = (const float*)d_in[9];
    const float* b2     = (const float*)d_in[10];
    const float* w3     = (const float*)d_in[11];
    const float* b3     = (const float*)d_in[12];
    float* out = (float*)d_out;

    char* p = (char*)d_ws;
    auto alloc = [&](size_t bytes) -> char* {
        char* r = p;
        p += (bytes + 255) & ~size_t(255);
        return r;
    };
    float* h       = (float*)alloc((size_t)N_NODES * D * 4);
    float* m       = (float*)alloc((size_t)N_NODES * D * 4);
    float* isq_src = (float*)alloc((size_t)N_NODES * 4);
    float* isq_dst = (float*)alloc((size_t)N_NODES * 4);
    int*   cnt     = (int*)alloc((size_t)2 * N_NODES * 4);
    int*   cnt_out = cnt;
    int*   cnt_in  = cnt + N_NODES;
    int*   row_ptr = (int*)alloc((size_t)(N_NODES + 1) * 4);
    int*   cursor  = (int*)alloc((size_t)N_NODES * 4);
    int*   csr_src = (int*)alloc((size_t)N_EDGES * 4);
    int*   bsums   = (int*)alloc(256 * 4);

    hipMemsetAsync(cnt, 0, (size_t)2 * N_NODES * 4, stream);
    count_deg_kernel<<<(N_EDGES + 255) / 256, 256, 0, stream>>>(src, dst, cnt_out, cnt_in);
    int nb = (N_NODES + 255) / 256;
    scan1_kernel<<<nb, 256, 0, stream>>>(cnt_in, row_ptr, bsums);
    scan2_kernel<<<1, 256, 0, stream>>>(bsums, nb);
    finalize_kernel<<<nb, 256, 0, stream>>>(bsums, row_ptr, cursor, cnt_out, cnt_in,
                                            isq_src, isq_dst);
    fill_csr_kernel<<<(N_EDGES + 255) / 256, 256, 0, stream>>>(src, dst, cursor, csr_src);
    init_h_kernel<<<N_NODES, 128, 0, stream>>>(labels, perms, emb, h);

    for (int l = 0; l < NLAYERS - 1; ++l) {
        aggregate_kernel<<<N_NODES / 4, 256, 0, stream>>>(h, row_ptr, csr_src,
                                                          isq_src, isq_dst, m);
        layer_kernel<<<(N_NODES + 127) / 128, 256, 0, stream>>>(
            m, Ws + (size_t)l * D * D, bs + (size_t)l * D, h);
    }
    aggregate_kernel<<<N_NODES / 4, 256, 0, stream>>>(h, row_ptr, csr_src,
                                                      isq_src, isq_dst, m);
    layer4_readout_kernel<<<(N_NODES + 63) / 64, 256, 0, stream>>>(
        m, Ws + (size_t)3 * D * D, bs + (size_t)3 * D, h,
        w1, b1, w2, b2, w3, b3, out);
}

// Round 4
// 662.911 us; speedup vs baseline: 1.2285x; 1.0342x over previous
//
#include <hip/hip_runtime.h>

#define N_NODES 50000
#define N_EDGES 800000
#define D 128
#define NLAYERS 4
#define NODES_PER 2000

// ---------------- degree histogram ----------------
__global__ void count_deg_kernel(const int* __restrict__ src, const int* __restrict__ dst,
                                 int* __restrict__ cnt_out, int* __restrict__ cnt_in) {
    int e = blockIdx.x * 256 + threadIdx.x;
    if (e < N_EDGES) {
        atomicAdd(&cnt_out[src[e]], 1);
        atomicAdd(&cnt_in[dst[e]], 1);
    }
}

__global__ void scan1_kernel(const int* __restrict__ cnt, int* __restrict__ excl,
                             int* __restrict__ bsums) {
    __shared__ int s[256];
    int t = threadIdx.x;
    int i = blockIdx.x * 256 + t;
    int v = (i < N_NODES) ? cnt[i] : 0;
    s[t] = v;
    __syncthreads();
    for (int off = 1; off < 256; off <<= 1) {
        int u = (t >= off) ? s[t - off] : 0;
        __syncthreads();
        s[t] += u;
        __syncthreads();
    }
    if (i < N_NODES) excl[i] = s[t] - v;
    if (t == 255) bsums[blockIdx.x] = s[255];
}

__global__ void scan2_kernel(int* __restrict__ bsums, int nb) {
    __shared__ int s[256];
    int t = threadIdx.x;
    int v = (t < nb) ? bsums[t] : 0;
    s[t] = v;
    __syncthreads();
    for (int off = 1; off < 256; off <<= 1) {
        int u = (t >= off) ? s[t - off] : 0;
        __syncthreads();
        s[t] += u;
        __syncthreads();
    }
    if (t < nb) bsums[t] = s[t] - v;
}

__global__ void finalize_kernel(const int* __restrict__ bsums, int* __restrict__ row_ptr,
                                int* __restrict__ cursor, const int* __restrict__ cnt_out,
                                const int* __restrict__ cnt_in, float* __restrict__ isq_src,
                                float* __restrict__ isq_dst) {
    int i = blockIdx.x * 256 + threadIdx.x;
    if (i < N_NODES) {
        int rp = row_ptr[i] + bsums[blockIdx.x];
        row_ptr[i] = rp;
        cursor[i] = rp;
        isq_src[i] = rsqrtf((float)max(cnt_out[i], 1));
        isq_dst[i] = rsqrtf((float)max(cnt_in[i], 1));
    }
    if (i == 0) row_ptr[N_NODES] = N_EDGES;
}

__global__ void fill_csr_kernel(const int* __restrict__ src, const int* __restrict__ dst,
                                int* __restrict__ cursor, int* __restrict__ csr_src) {
    int e = blockIdx.x * 256 + threadIdx.x;
    if (e < N_EDGES) {
        int pos = atomicAdd(&cursor[dst[e]], 1);
        csr_src[pos] = src[e];
    }
}

// ---------------- h = emb[labels] + positional encoding ----------------
__global__ void init_h_kernel(const int* __restrict__ labels, const int* __restrict__ perms,
                              const float* __restrict__ emb, float* __restrict__ h) {
    int b = blockIdx.x;
    int g = b / NODES_PER;
    int i = b - g * NODES_PER;
    int node = g * NODES_PER + perms[b];
    int d = threadIdx.x;
    int k = d >> 1;
    float ang = (float)(i + 1) * expf((float)(2 * k) * (-9.210340371976184f / 128.0f));
    float pe = (d & 1) ? cosf(ang) : sinf(ang);
    h[node * D + d] = emb[labels[node] * D + d] + pe;
}

// ---------------- m[v] = isq_dst[v] * sum_{e: dst=v} isq_src[s] * h[s] ----------------
// one 64-lane wave per node; half-wave per edge, float4 per lane (2 edges / vmem instr)
__global__ __launch_bounds__(256) void aggregate_kernel(const float* __restrict__ h,
        const int* __restrict__ row_ptr, const int* __restrict__ csr_src,
        const float* __restrict__ isq_src, const float* __restrict__ isq_dst,
        float* __restrict__ m) {
    int node = blockIdx.x * 4 + (threadIdx.x >> 6);
    int lane = threadIdx.x & 63;
    int half = lane >> 5;
    int col = lane & 31;
    int start = row_ptr[node], end = row_ptr[node + 1];
    const float* hb = h + col * 4;
    float ax = 0.f, ay = 0.f, az = 0.f, aw = 0.f;
    int e = start;
    for (; e + 8 <= end; e += 8) {
        int i0 = e + half;
        int s0 = csr_src[i0 + 0];
        int s1 = csr_src[i0 + 2];
        int s2 = csr_src[i0 + 4];
        int s3 = csr_src[i0 + 6];
        float w0 = isq_src[s0], w1 = isq_src[s1], w2 = isq_src[s2], w3 = isq_src[s3];
        float4 v0 = *(const float4*)&hb[s0 * D];
        float4 v1 = *(const float4*)&hb[s1 * D];
        float4 v2 = *(const float4*)&hb[s2 * D];
        float4 v3 = *(const float4*)&hb[s3 * D];
        ax += w0 * v0.x; ay += w0 * v0.y; az += w0 * v0.z; aw += w0 * v0.w;
        ax += w1 * v1.x; ay += w1 * v1.y; az += w1 * v1.z; aw += w1 * v1.w;
        ax += w2 * v2.x; ay += w2 * v2.y; az += w2 * v2.z; aw += w2 * v2.w;
        ax += w3 * v3.x; ay += w3 * v3.y; az += w3 * v3.z; aw += w3 * v3.w;
    }
    for (; e + 2 <= end; e += 2) {
        int s = csr_src[e + half];
        float w = isq_src[s];
        float4 v = *(const float4*)&hb[s * D];
        ax += w * v.x; ay += w * v.y; az += w * v.z; aw += w * v.w;
    }
    if (half == 0 && e < end) {
        int s = csr_src[e];
        float w = isq_src[s];
        float4 v = *(const float4*)&hb[s * D];
        ax += w * v.x; ay += w * v.y; az += w * v.z; aw += w * v.w;
    }
    // combine the two half-wave partials
    ax += __shfl_xor(ax, 32, 64);
    ay += __shfl_xor(ay, 32, 64);
    az += __shfl_xor(az, 32, 64);
    aw += __shfl_xor(aw, 32, 64);
    if (half == 0) {
        float wd = isq_dst[node];
        *(float4*)&m[node * D + col * 4] = make_float4(ax * wd, ay * wd, az * wd, aw * wd);
    }
}

// ---------------- h = relu(m @ W + b) + h : 128x128 tile, 8x8/thread, swizzled msT -------
__global__ __launch_bounds__(256) void layer_kernel(const float* __restrict__ m,
                                                    const float* __restrict__ W,
                                                    const float* __restrict__ bias,
                                                    float* __restrict__ h) {
    __shared__ float msT[128][132];
    int t = threadIdx.x;
    int rowbase = blockIdx.x * 128;

    for (int i = t; i < 4096; i += 256) {
        int row = i >> 5;
        int kc = i & 31;
        int grow = rowbase + row;
        float4 v = (grow < N_NODES) ? *(const float4*)&m[grow * D + kc * 4]
                                    : make_float4(0.f, 0.f, 0.f, 0.f);
        int cs = row ^ ((kc & 7) << 2);
        msT[kc * 4 + 0][cs] = v.x;
        msT[kc * 4 + 1][cs] = v.y;
        msT[kc * 4 + 2][cs] = v.z;
        msT[kc * 4 + 3][cs] = v.w;
    }
    __syncthreads();

    int tx = t & 15, ty = t >> 4;
    int c0 = tx * 8;
    int r0 = ty * 8;
    float acc[8][8];
    float4 bv0 = *(const float4*)&bias[c0];
    float4 bv1 = *(const float4*)&bias[c0 + 4];
#pragma unroll
    for (int i = 0; i < 8; ++i) {
        acc[i][0] = bv0.x; acc[i][1] = bv0.y; acc[i][2] = bv0.z; acc[i][3] = bv0.w;
        acc[i][4] = bv1.x; acc[i][5] = bv1.y; acc[i][6] = bv1.z; acc[i][7] = bv1.w;
    }
#pragma unroll 4
    for (int k = 0; k < 128; ++k) {
        int s4 = ((k >> 2) & 7) << 2;
        float4 wa = *(const float4*)&W[k * D + c0];
        float4 wb = *(const float4*)&W[k * D + c0 + 4];
        float4 ma = *(const float4*)&msT[k][r0 ^ s4];
        float4 mb = *(const float4*)&msT[k][(r0 + 4) ^ s4];
        float mv[8] = {ma.x, ma.y, ma.z, ma.w, mb.x, mb.y, mb.z, mb.w};
        float wv[8] = {wa.x, wa.y, wa.z, wa.w, wb.x, wb.y, wb.z, wb.w};
#pragma unroll
        for (int i = 0; i < 8; ++i)
#pragma unroll
            for (int j = 0; j < 8; ++j)
                acc[i][j] += mv[i] * wv[j];
    }
#pragma unroll
    for (int i = 0; i < 8; ++i) {
        int row = rowbase + r0 + i;
        if (row < N_NODES) {
            float4 h0 = *(const float4*)&h[row * D + c0];
            float4 h1 = *(const float4*)&h[row * D + c0 + 4];
            float4 o0, o1;
            o0.x = fmaxf(acc[i][0], 0.f) + h0.x;
            o0.y = fmaxf(acc[i][1], 0.f) + h0.y;
            o0.z = fmaxf(acc[i][2], 0.f) + h0.z;
            o0.w = fmaxf(acc[i][3], 0.f) + h0.w;
            o1.x = fmaxf(acc[i][4], 0.f) + h1.x;
            o1.y = fmaxf(acc[i][5], 0.f) + h1.y;
            o1.z = fmaxf(acc[i][6], 0.f) + h1.z;
            o1.w = fmaxf(acc[i][7], 0.f) + h1.w;
            *(float4*)&h[row * D + c0] = o0;
            *(float4*)&h[row * D + c0 + 4] = o1;
        }
    }
}

// ---------------- MLP readout: 64-row tile, 256 threads, 34.8 KB LDS ----------------
// hT[128][68] staged once; region reused: y1T -> rows 0..63, y2T -> rows 64..95.
__global__ __launch_bounds__(256) void readout_kernel(const float* __restrict__ h,
        const float* __restrict__ w1, const float* __restrict__ b1,
        const float* __restrict__ w2, const float* __restrict__ b2,
        const float* __restrict__ w3, const float* __restrict__ b3,
        float* __restrict__ out) {
    __shared__ float hT[128][68];
    int t = threadIdx.x;
    int rowbase = blockIdx.x * 64;
    int tx = t & 15, ty = t >> 4;
    int r0 = ty * 4;

    // stage h^T (swizzled): 64 rows x 32 float4-chunks
    for (int i = t; i < 2048; i += 256) {
        int row = i >> 5;
        int kc = i & 31;
        int grow = rowbase + row;
        float4 v = (grow < N_NODES) ? *(const float4*)&h[grow * D + kc * 4]
                                    : make_float4(0.f, 0.f, 0.f, 0.f);
        int cs = row ^ ((kc & 7) << 2);
        hT[kc * 4 + 0][cs] = v.x;
        hT[kc * 4 + 1][cs] = v.y;
        hT[kc * 4 + 2][cs] = v.z;
        hT[kc * 4 + 3][cs] = v.w;
    }
    __syncthreads();

    // stage1: y1 = relu(h @ w1 + b1) : 64x64, thread tile 4x4
    float a1[4][4];
    {
        int c1 = tx * 4;
        float4 bv = *(const float4*)&b1[c1];
#pragma unroll
        for (int i = 0; i < 4; ++i) {
            a1[i][0] = bv.x; a1[i][1] = bv.y; a1[i][2] = bv.z; a1[i][3] = bv.w;
        }
#pragma unroll 4
        for (int k = 0; k < 128; ++k) {
            int s4 = ((k >> 2) & 7) << 2;
            float4 ma = *(const float4*)&hT[k][r0 ^ s4];
            float4 wv = *(const float4*)&w1[k * 64 + c1];
            float mv[4] = {ma.x, ma.y, ma.z, ma.w};
#pragma unroll
            for (int i = 0; i < 4; ++i) {
                a1[i][0] += mv[i] * wv.x;
                a1[i][1] += mv[i] * wv.y;
                a1[i][2] += mv[i] * wv.z;
                a1[i][3] += mv[i] * wv.w;
            }
        }
    }
    __syncthreads();   // all hT reads done
    {
        int c1 = tx * 4;
#pragma unroll
        for (int j = 0; j < 4; ++j) {
            int c = c1 + j;
            int cs = r0 ^ (((c >> 2) & 7) << 2);
            *(float4*)&hT[c][cs] = make_float4(fmaxf(a1[0][j], 0.f), fmaxf(a1[1][j], 0.f),
                                               fmaxf(a1[2][j], 0.f), fmaxf(a1[3][j], 0.f));
        }
    }
    __syncthreads();

    // stage2: y2 = relu(y1 @ w2 + b2) : 64x32, thread tile 4x2; y2T -> rows 64..95 (disjoint)
    {
        int c2 = tx * 2;
        float a2[4][2];
        float2 bv = *(const float2*)&b2[c2];
#pragma unroll
        for (int i = 0; i < 4; ++i) { a2[i][0] = bv.x; a2[i][1] = bv.y; }
#pragma unroll 4
        for (int k = 0; k < 64; ++k) {
            int s4 = ((k >> 2) & 7) << 2;
            float4 ma = *(const float4*)&hT[k][r0 ^ s4];
            float2 wv = *(const float2*)&w2[k * 32 + c2];
            float mv[4] = {ma.x, ma.y, ma.z, ma.w};
#pragma unroll
            for (int i = 0; i < 4; ++i) {
                a2[i][0] += mv[i] * wv.x;
                a2[i][1] += mv[i] * wv.y;
            }
        }
#pragma unroll
        for (int j = 0; j < 2; ++j) {
            int c = c2 + j;
            int cs = r0 ^ (((c >> 2) & 7) << 2);
            *(float4*)&hT[64 + c][cs] = make_float4(fmaxf(a2[0][j], 0.f), fmaxf(a2[1][j], 0.f),
                                                    fmaxf(a2[2][j], 0.f), fmaxf(a2[3][j], 0.f));
        }
    }
    __syncthreads();

    // stage3: out = y2 @ w3 + b3 : 64x128, thread tile 4x8
    {
        int c0 = tx * 8;
        float acc[4][8];
        float4 bv0 = *(const float4*)&b3[c0];
        float4 bv1 = *(const float4*)&b3[c0 + 4];
#pragma unroll
        for (int i = 0; i < 4; ++i) {
            acc[i][0] = bv0.x; acc[i][1] = bv0.y; acc[i][2] = bv0.z; acc[i][3] = bv0.w;
            acc[i][4] = bv1.x; acc[i][5] = bv1.y; acc[i][6] = bv1.z; acc[i][7] = bv1.w;
        }
#pragma unroll
        for (int k = 0; k < 32; ++k) {
            int s4 = ((k >> 2) & 7) << 2;
            float4 ma = *(const float4*)&hT[64 + k][r0 ^ s4];
            float4 wa = *(const float4*)&w3[k * D + c0];
            float4 wb = *(const float4*)&w3[k * D + c0 + 4];
            float mv[4] = {ma.x, ma.y, ma.z, ma.w};
            float wv[8] = {wa.x, wa.y, wa.z, wa.w, wb.x, wb.y, wb.z, wb.w};
#pragma unroll
            for (int i = 0; i < 4; ++i)
#pragma unroll
                for (int j = 0; j < 8; ++j)
                    acc[i][j] += mv[i] * wv[j];
        }
#pragma unroll
        for (int i = 0; i < 4; ++i) {
            int row = rowbase + r0 + i;
            if (row < N_NODES) {
                *(float4*)&out[row * D + c0] =
                    make_float4(acc[i][0], acc[i][1], acc[i][2], acc[i][3]);
                *(float4*)&out[row * D + c0 + 4] =
                    make_float4(acc[i][4], acc[i][5], acc[i][6], acc[i][7]);
            }
        }
    }
}

extern "C" void kernel_launch(void* const* d_in, const int* in_sizes, int n_in,
                              void* d_out, int out_size, void* d_ws, size_t ws_size,
                              hipStream_t stream) {
    const int*   labels = (const int*)d_in[0];
    const int*   src    = (const int*)d_in[1];
    const int*   dst    = (const int*)d_in[2];
    const int*   perms  = (const int*)d_in[3];
    const float* emb    = (const float*)d_in[4];
    const float* Ws     = (const float*)d_in[5];
    const float* bs     = (const float*)d_in[6];
    const float* w1     = (const float*)d_in[7];
    const float* b1     = (const float*)d_in[8];
    const float* w2     = (const float*)d_in[9];
    const float* b2     = (const float*)d_in[10];
    const float* w3     = (const float*)d_in[11];
    const float* b3     = (const float*)d_in[12];
    float* out = (float*)d_out;

    char* p = (char*)d_ws;
    auto alloc = [&](size_t bytes) -> char* {
        char* r = p;
        p += (bytes + 255) & ~size_t(255);
        return r;
    };
    float* h       = (float*)alloc((size_t)N_NODES * D * 4);
    float* m       = (float*)alloc((size_t)N_NODES * D * 4);
    float* isq_src = (float*)alloc((size_t)N_NODES * 4);
    float* isq_dst = (float*)alloc((size_t)N_NODES * 4);
    int*   cnt     = (int*)alloc((size_t)2 * N_NODES * 4);
    int*   cnt_out = cnt;
    int*   cnt_in  = cnt + N_NODES;
    int*   row_ptr = (int*)alloc((size_t)(N_NODES + 1) * 4);
    int*   cursor  = (int*)alloc((size_t)N_NODES * 4);
    int*   csr_src = (int*)alloc((size_t)N_EDGES * 4);
    int*   bsums   = (int*)alloc(256 * 4);

    hipMemsetAsync(cnt, 0, (size_t)2 * N_NODES * 4, stream);
    count_deg_kernel<<<(N_EDGES + 255) / 256, 256, 0, stream>>>(src, dst, cnt_out, cnt_in);
    int nb = (N_NODES + 255) / 256;
    scan1_kernel<<<nb, 256, 0, stream>>>(cnt_in, row_ptr, bsums);
    scan2_kernel<<<1, 256, 0, stream>>>(bsums, nb);
    finalize_kernel<<<nb, 256, 0, stream>>>(bsums, row_ptr, cursor, cnt_out, cnt_in,
                                            isq_src, isq_dst);
    fill_csr_kernel<<<(N_EDGES + 255) / 256, 256, 0, stream>>>(src, dst, cursor, csr_src);
    init_h_kernel<<<N_NODES, 128, 0, stream>>>(labels, perms, emb, h);

    for (int l = 0; l < NLAYERS; ++l) {
        aggregate_kernel<<<N_NODES / 4, 256, 0, stream>>>(h, row_ptr, csr_src,
                                                          isq_src, isq_dst, m);
        layer_kernel<<<(N_NODES + 127) / 128, 256, 0, stream>>>(
            m, Ws + (size_t)l * D * D, bs + (size_t)l * D, h);
    }
    readout_kernel<<<(N_NODES + 63) / 64, 256, 0, stream>>>(h, w1, b1, w2, b2, w3, b3, out);
}

// Round 5
// 578.809 us; speedup vs baseline: 1.4070x; 1.1453x over previous
//
#include <hip/hip_runtime.h>

#define N_NODES 50000
#define N_EDGES 800000
#define D 128
#define NLAYERS 4
#define NODES_PER 2000

// ---- bf16 helpers (RNE round, bit tricks; no lib calls) ----
__device__ inline unsigned rne16(float f) {
    unsigned u = __float_as_uint(f);
    return (u + 0x7fffu + ((u >> 16) & 1u)) >> 16;
}
__device__ inline unsigned pack_bf2(float a, float b) {
    return rne16(a) | (rne16(b) << 16);
}
__device__ inline float4 bf4_to_f4(uint2 v) {
    float4 r;
    r.x = __uint_as_float(v.x << 16);
    r.y = __uint_as_float(v.x & 0xffff0000u);
    r.z = __uint_as_float(v.y << 16);
    r.w = __uint_as_float(v.y & 0xffff0000u);
    return r;
}

// ---------------- degree histogram ----------------
__global__ void count_deg_kernel(const int* __restrict__ src, const int* __restrict__ dst,
                                 int* __restrict__ cnt_out, int* __restrict__ cnt_in) {
    int e = blockIdx.x * 256 + threadIdx.x;
    if (e < N_EDGES) {
        atomicAdd(&cnt_out[src[e]], 1);
        atomicAdd(&cnt_in[dst[e]], 1);
    }
}

__global__ void scan1_kernel(const int* __restrict__ cnt, int* __restrict__ excl,
                             int* __restrict__ bsums) {
    __shared__ int s[256];
    int t = threadIdx.x;
    int i = blockIdx.x * 256 + t;
    int v = (i < N_NODES) ? cnt[i] : 0;
    s[t] = v;
    __syncthreads();
    for (int off = 1; off < 256; off <<= 1) {
        int u = (t >= off) ? s[t - off] : 0;
        __syncthreads();
        s[t] += u;
        __syncthreads();
    }
    if (i < N_NODES) excl[i] = s[t] - v;
    if (t == 255) bsums[blockIdx.x] = s[255];
}

__global__ void scan2_kernel(int* __restrict__ bsums, int nb) {
    __shared__ int s[256];
    int t = threadIdx.x;
    int v = (t < nb) ? bsums[t] : 0;
    s[t] = v;
    __syncthreads();
    for (int off = 1; off < 256; off <<= 1) {
        int u = (t >= off) ? s[t - off] : 0;
        __syncthreads();
        s[t] += u;
        __syncthreads();
    }
    if (t < nb) bsums[t] = s[t] - v;
}

__global__ void finalize_kernel(const int* __restrict__ bsums, int* __restrict__ row_ptr,
                                int* __restrict__ cursor, const int* __restrict__ cnt_out,
                                const int* __restrict__ cnt_in, float* __restrict__ isq_src,
                                float* __restrict__ isq_dst) {
    int i = blockIdx.x * 256 + threadIdx.x;
    if (i < N_NODES) {
        int rp = row_ptr[i] + bsums[blockIdx.x];
        row_ptr[i] = rp;
        cursor[i] = rp;
        isq_src[i] = rsqrtf((float)max(cnt_out[i], 1));
        isq_dst[i] = rsqrtf((float)max(cnt_in[i], 1));
    }
    if (i == 0) row_ptr[N_NODES] = N_EDGES;
}

__global__ void fill_csr_kernel(const int* __restrict__ src, const int* __restrict__ dst,
                                int* __restrict__ cursor, int* __restrict__ csr_src) {
    int e = blockIdx.x * 256 + threadIdx.x;
    if (e < N_EDGES) {
        int pos = atomicAdd(&cursor[dst[e]], 1);
        csr_src[pos] = src[e];
    }
}

// ---------------- h = emb[labels] + positional encoding (f32 + bf16 shadow) -------------
__global__ void init_h_kernel(const int* __restrict__ labels, const int* __restrict__ perms,
                              const float* __restrict__ emb, float* __restrict__ h,
                              unsigned short* __restrict__ h16) {
    int b = blockIdx.x;
    int g = b / NODES_PER;
    int i = b - g * NODES_PER;
    int node = g * NODES_PER + perms[b];
    int d = threadIdx.x;
    int k = d >> 1;
    float ang = (float)(i + 1) * expf((float)(2 * k) * (-9.210340371976184f / 128.0f));
    float pe = (d & 1) ? cosf(ang) : sinf(ang);
    float v = emb[labels[node] * D + d] + pe;
    h[node * D + d] = v;
    h16[node * D + d] = (unsigned short)rne16(v);
}

// ---------------- m16[v] = bf16( isq_dst[v] * sum isq_src[s] * h16[s] ) -----------------
// one wave per node; half-wave per edge, 4xbf16 (8B) per lane -> 256B row per half-wave
__global__ __launch_bounds__(256) void aggregate_kernel(const unsigned short* __restrict__ h16,
        const int* __restrict__ row_ptr, const int* __restrict__ csr_src,
        const float* __restrict__ isq_src, const float* __restrict__ isq_dst,
        unsigned short* __restrict__ m16) {
    int node = blockIdx.x * 4 + (threadIdx.x >> 6);
    int lane = threadIdx.x & 63;
    int half = lane >> 5;
    int col = lane & 31;
    int start = row_ptr[node], end = row_ptr[node + 1];
    const unsigned short* hb = h16 + col * 4;
    float ax = 0.f, ay = 0.f, az = 0.f, aw = 0.f;
    int e = start;
    for (; e + 8 <= end; e += 8) {
        int i0 = e + half;
        int s0 = csr_src[i0 + 0];
        int s1 = csr_src[i0 + 2];
        int s2 = csr_src[i0 + 4];
        int s3 = csr_src[i0 + 6];
        float w0 = isq_src[s0], w1 = isq_src[s1], w2 = isq_src[s2], w3 = isq_src[s3];
        float4 v0 = bf4_to_f4(*(const uint2*)&hb[s0 * D]);
        float4 v1 = bf4_to_f4(*(const uint2*)&hb[s1 * D]);
        float4 v2 = bf4_to_f4(*(const uint2*)&hb[s2 * D]);
        float4 v3 = bf4_to_f4(*(const uint2*)&hb[s3 * D]);
        ax += w0 * v0.x; ay += w0 * v0.y; az += w0 * v0.z; aw += w0 * v0.w;
        ax += w1 * v1.x; ay += w1 * v1.y; az += w1 * v1.z; aw += w1 * v1.w;
        ax += w2 * v2.x; ay += w2 * v2.y; az += w2 * v2.z; aw += w2 * v2.w;
        ax += w3 * v3.x; ay += w3 * v3.y; az += w3 * v3.z; aw += w3 * v3.w;
    }
    for (; e + 2 <= end; e += 2) {
        int s = csr_src[e + half];
        float w = isq_src[s];
        float4 v = bf4_to_f4(*(const uint2*)&hb[s * D]);
        ax += w * v.x; ay += w * v.y; az += w * v.z; aw += w * v.w;
    }
    if (half == 0 && e < end) {
        int s = csr_src[e];
        float w = isq_src[s];
        float4 v = bf4_to_f4(*(const uint2*)&hb[s * D]);
        ax += w * v.x; ay += w * v.y; az += w * v.z; aw += w * v.w;
    }
    ax += __shfl_xor(ax, 32, 64);
    ay += __shfl_xor(ay, 32, 64);
    az += __shfl_xor(az, 32, 64);
    aw += __shfl_xor(aw, 32, 64);
    if (half == 0) {
        float wd = isq_dst[node];
        uint2 o;
        o.x = pack_bf2(ax * wd, ay * wd);
        o.y = pack_bf2(az * wd, aw * wd);
        *(uint2*)&m16[node * D + col * 4] = o;
    }
}

// ------- h = relu(m @ W + b) + h : 64-row x 128-col tile, 4x8/thread, swizzled msT -------
// also maintains bf16 shadow h16 for the next layer's gather
__global__ __launch_bounds__(256) void layer_kernel(const unsigned short* __restrict__ m16,
                                                    const float* __restrict__ W,
                                                    const float* __restrict__ bias,
                                                    float* __restrict__ h,
                                                    unsigned short* __restrict__ h16) {
    __shared__ float msT[128][68];
    int t = threadIdx.x;
    int rowbase = blockIdx.x * 64;

    for (int i = t; i < 2048; i += 256) {
        int row = i >> 5;
        int kc = i & 31;
        int grow = rowbase + row;
        float4 v = make_float4(0.f, 0.f, 0.f, 0.f);
        if (grow < N_NODES) v = bf4_to_f4(*(const uint2*)&m16[grow * D + kc * 4]);
        int cs = row ^ ((kc & 7) << 2);
        msT[kc * 4 + 0][cs] = v.x;
        msT[kc * 4 + 1][cs] = v.y;
        msT[kc * 4 + 2][cs] = v.z;
        msT[kc * 4 + 3][cs] = v.w;
    }
    __syncthreads();

    int tx = t & 15, ty = t >> 4;
    int c0 = tx * 8;
    int r0 = ty * 4;
    float acc[4][8];
    float4 bv0 = *(const float4*)&bias[c0];
    float4 bv1 = *(const float4*)&bias[c0 + 4];
#pragma unroll
    for (int i = 0; i < 4; ++i) {
        acc[i][0] = bv0.x; acc[i][1] = bv0.y; acc[i][2] = bv0.z; acc[i][3] = bv0.w;
        acc[i][4] = bv1.x; acc[i][5] = bv1.y; acc[i][6] = bv1.z; acc[i][7] = bv1.w;
    }
#pragma unroll 4
    for (int k = 0; k < 128; ++k) {
        int s4 = ((k >> 2) & 7) << 2;
        float4 wa = *(const float4*)&W[k * D + c0];
        float4 wb = *(const float4*)&W[k * D + c0 + 4];
        float4 ma = *(const float4*)&msT[k][r0 ^ s4];
        float mv[4] = {ma.x, ma.y, ma.z, ma.w};
        float wv[8] = {wa.x, wa.y, wa.z, wa.w, wb.x, wb.y, wb.z, wb.w};
#pragma unroll
        for (int i = 0; i < 4; ++i)
#pragma unroll
            for (int j = 0; j < 8; ++j)
                acc[i][j] += mv[i] * wv[j];
    }
#pragma unroll
    for (int i = 0; i < 4; ++i) {
        int row = rowbase + r0 + i;
        if (row < N_NODES) {
            float4 h0 = *(const float4*)&h[row * D + c0];
            float4 h1 = *(const float4*)&h[row * D + c0 + 4];
            float4 o0, o1;
            o0.x = fmaxf(acc[i][0], 0.f) + h0.x;
            o0.y = fmaxf(acc[i][1], 0.f) + h0.y;
            o0.z = fmaxf(acc[i][2], 0.f) + h0.z;
            o0.w = fmaxf(acc[i][3], 0.f) + h0.w;
            o1.x = fmaxf(acc[i][4], 0.f) + h1.x;
            o1.y = fmaxf(acc[i][5], 0.f) + h1.y;
            o1.z = fmaxf(acc[i][6], 0.f) + h1.z;
            o1.w = fmaxf(acc[i][7], 0.f) + h1.w;
            *(float4*)&h[row * D + c0] = o0;
            *(float4*)&h[row * D + c0 + 4] = o1;
            uint4 p;
            p.x = pack_bf2(o0.x, o0.y);
            p.y = pack_bf2(o0.z, o0.w);
            p.z = pack_bf2(o1.x, o1.y);
            p.w = pack_bf2(o1.z, o1.w);
            *(uint4*)&h16[row * D + c0] = p;
        }
    }
}

// ---------------- MLP readout: 64-row tile, 256 threads, 34.8 KB LDS ----------------
__global__ __launch_bounds__(256, 4) void readout_kernel(const float* __restrict__ h,
        const float* __restrict__ w1, const float* __restrict__ b1,
        const float* __restrict__ w2, const float* __restrict__ b2,
        const float* __restrict__ w3, const float* __restrict__ b3,
        float* __restrict__ out) {
    __shared__ float hT[128][68];
    int t = threadIdx.x;
    int rowbase = blockIdx.x * 64;
    int tx = t & 15, ty = t >> 4;
    int r0 = ty * 4;

    for (int i = t; i < 2048; i += 256) {
        int row = i >> 5;
        int kc = i & 31;
        int grow = rowbase + row;
        float4 v = (grow < N_NODES) ? *(const float4*)&h[grow * D + kc * 4]
                                    : make_float4(0.f, 0.f, 0.f, 0.f);
        int cs = row ^ ((kc & 7) << 2);
        hT[kc * 4 + 0][cs] = v.x;
        hT[kc * 4 + 1][cs] = v.y;
        hT[kc * 4 + 2][cs] = v.z;
        hT[kc * 4 + 3][cs] = v.w;
    }
    __syncthreads();

    // stage1: y1 = relu(h @ w1 + b1) : 64x64, thread tile 4x4
    float a1[4][4];
    {
        int c1 = tx * 4;
        float4 bv = *(const float4*)&b1[c1];
#pragma unroll
        for (int i = 0; i < 4; ++i) {
            a1[i][0] = bv.x; a1[i][1] = bv.y; a1[i][2] = bv.z; a1[i][3] = bv.w;
        }
#pragma unroll 2
        for (int k = 0; k < 128; ++k) {
            int s4 = ((k >> 2) & 7) << 2;
            float4 ma = *(const float4*)&hT[k][r0 ^ s4];
            float4 wv = *(const float4*)&w1[k * 64 + c1];
            float mv[4] = {ma.x, ma.y, ma.z, ma.w};
#pragma unroll
            for (int i = 0; i < 4; ++i) {
                a1[i][0] += mv[i] * wv.x;
                a1[i][1] += mv[i] * wv.y;
                a1[i][2] += mv[i] * wv.z;
                a1[i][3] += mv[i] * wv.w;
            }
        }
    }
    __syncthreads();
    {
        int c1 = tx * 4;
#pragma unroll
        for (int j = 0; j < 4; ++j) {
            int c = c1 + j;
            int cs = r0 ^ (((c >> 2) & 7) << 2);
            *(float4*)&hT[c][cs] = make_float4(fmaxf(a1[0][j], 0.f), fmaxf(a1[1][j], 0.f),
                                               fmaxf(a1[2][j], 0.f), fmaxf(a1[3][j], 0.f));
        }
    }
    __syncthreads();

    // stage2: y2 = relu(y1 @ w2 + b2) : 64x32, thread tile 4x2; y2T -> rows 64..95
    {
        int c2 = tx * 2;
        float a2[4][2];
        float2 bv = *(const float2*)&b2[c2];
#pragma unroll
        for (int i = 0; i < 4; ++i) { a2[i][0] = bv.x; a2[i][1] = bv.y; }
#pragma unroll 2
        for (int k = 0; k < 64; ++k) {
            int s4 = ((k >> 2) & 7) << 2;
            float4 ma = *(const float4*)&hT[k][r0 ^ s4];
            float2 wv = *(const float2*)&w2[k * 32 + c2];
            float mv[4] = {ma.x, ma.y, ma.z, ma.w};
#pragma unroll
            for (int i = 0; i < 4; ++i) {
                a2[i][0] += mv[i] * wv.x;
                a2[i][1] += mv[i] * wv.y;
            }
        }
#pragma unroll
        for (int j = 0; j < 2; ++j) {
            int c = c2 + j;
            int cs = r0 ^ (((c >> 2) & 7) << 2);
            *(float4*)&hT[64 + c][cs] = make_float4(fmaxf(a2[0][j], 0.f), fmaxf(a2[1][j], 0.f),
                                                    fmaxf(a2[2][j], 0.f), fmaxf(a2[3][j], 0.f));
        }
    }
    __syncthreads();

    // stage3: out = y2 @ w3 + b3 : 64x128, thread tile 4x8
    {
        int c0 = tx * 8;
        float acc[4][8];
        float4 bv0 = *(const float4*)&b3[c0];
        float4 bv1 = *(const float4*)&b3[c0 + 4];
#pragma unroll
        for (int i = 0; i < 4; ++i) {
            acc[i][0] = bv0.x; acc[i][1] = bv0.y; acc[i][2] = bv0.z; acc[i][3] = bv0.w;
            acc[i][4] = bv1.x; acc[i][5] = bv1.y; acc[i][6] = bv1.z; acc[i][7] = bv1.w;
        }
#pragma unroll 4
        for (int k = 0; k < 32; ++k) {
            int s4 = ((k >> 2) & 7) << 2;
            float4 ma = *(const float4*)&hT[64 + k][r0 ^ s4];
            float4 wa = *(const float4*)&w3[k * D + c0];
            float4 wb = *(const float4*)&w3[k * D + c0 + 4];
            float mv[4] = {ma.x, ma.y, ma.z, ma.w};
            float wv[8] = {wa.x, wa.y, wa.z, wa.w, wb.x, wb.y, wb.z, wb.w};
#pragma unroll
            for (int i = 0; i < 4; ++i)
#pragma unroll
                for (int j = 0; j < 8; ++j)
                    acc[i][j] += mv[i] * wv[j];
        }
#pragma unroll
        for (int i = 0; i < 4; ++i) {
            int row = rowbase + r0 + i;
            if (row < N_NODES) {
                *(float4*)&out[row * D + c0] =
                    make_float4(acc[i][0], acc[i][1], acc[i][2], acc[i][3]);
                *(float4*)&out[row * D + c0 + 4] =
                    make_float4(acc[i][4], acc[i][5], acc[i][6], acc[i][7]);
            }
        }
    }
}

extern "C" void kernel_launch(void* const* d_in, const int* in_sizes, int n_in,
                              void* d_out, int out_size, void* d_ws, size_t ws_size,
                              hipStream_t stream) {
    const int*   labels = (const int*)d_in[0];
    const int*   src    = (const int*)d_in[1];
    const int*   dst    = (const int*)d_in[2];
    const int*   perms  = (const int*)d_in[3];
    const float* emb    = (const float*)d_in[4];
    const float* Ws     = (const float*)d_in[5];
    const float* bs     = (const float*)d_in[6];
    const float* w1     = (const float*)d_in[7];
    const float* b1     = (const float*)d_in[8];
    const float* w2     = (const float*)d_in[9];
    const float* b2     = (const float*)d_in[10];
    const float* w3     = (const float*)d_in[11];
    const float* b3     = (const float*)d_in[12];
    float* out = (float*)d_out;

    char* p = (char*)d_ws;
    auto alloc = [&](size_t bytes) -> char* {
        char* r = p;
        p += (bytes + 255) & ~size_t(255);
        return r;
    };
    float*          h       = (float*)alloc((size_t)N_NODES * D * 4);
    unsigned short* h16     = (unsigned short*)alloc((size_t)N_NODES * D * 2);
    unsigned short* m16     = (unsigned short*)alloc((size_t)N_NODES * D * 2);
    float*          isq_src = (float*)alloc((size_t)N_NODES * 4);
    float*          isq_dst = (float*)alloc((size_t)N_NODES * 4);
    int*            cnt     = (int*)alloc((size_t)2 * N_NODES * 4);
    int*            cnt_out = cnt;
    int*            cnt_in  = cnt + N_NODES;
    int*            row_ptr = (int*)alloc((size_t)(N_NODES + 1) * 4);
    int*            cursor  = (int*)alloc((size_t)N_NODES * 4);
    int*            csr_src = (int*)alloc((size_t)N_EDGES * 4);
    int*            bsums   = (int*)alloc(256 * 4);

    hipMemsetAsync(cnt, 0, (size_t)2 * N_NODES * 4, stream);
    count_deg_kernel<<<(N_EDGES + 255) / 256, 256, 0, stream>>>(src, dst, cnt_out, cnt_in);
    int nb = (N_NODES + 255) / 256;
    scan1_kernel<<<nb, 256, 0, stream>>>(cnt_in, row_ptr, bsums);
    scan2_kernel<<<1, 256, 0, stream>>>(bsums, nb);
    finalize_kernel<<<nb, 256, 0, stream>>>(bsums, row_ptr, cursor, cnt_out, cnt_in,
                                            isq_src, isq_dst);
    fill_csr_kernel<<<(N_EDGES + 255) / 256, 256, 0, stream>>>(src, dst, cursor, csr_src);
    init_h_kernel<<<N_NODES, 128, 0, stream>>>(labels, perms, emb, h, h16);

    for (int l = 0; l < NLAYERS; ++l) {
        aggregate_kernel<<<N_NODES / 4, 256, 0, stream>>>(h16, row_ptr, csr_src,
                                                          isq_src, isq_dst, m16);
        layer_kernel<<<(N_NODES + 63) / 64, 256, 0, stream>>>(
            m16, Ws + (size_t)l * D * D, bs + (size_t)l * D, h, h16);
    }
    readout_kernel<<<(N_NODES + 63) / 64, 256, 0, stream>>>(h, w1, b1, w2, b2, w3, b3, out);
}

// Round 6
// 515.191 us; speedup vs baseline: 1.5808x; 1.1235x over previous
//
#include <hip/hip_runtime.h>

#define N_NODES 50000
#define N_EDGES 800000
#define D 128
#define NLAYERS 4
#define NODES_PER 2000
#define CAP 64          // bucket capacity per node; P(Poisson(16) >= 64) ~ 1e-20

// ---- bf16 helpers (RNE round, bit tricks) ----
__device__ inline unsigned rne16(float f) {
    unsigned u = __float_as_uint(f);
    return (u + 0x7fffu + ((u >> 16) & 1u)) >> 16;
}
__device__ inline unsigned pack_bf2(float a, float b) {
    return rne16(a) | (rne16(b) << 16);
}
__device__ inline float4 bf4_to_f4(uint2 v) {
    float4 r;
    r.x = __uint_as_float(v.x << 16);
    r.y = __uint_as_float(v.x & 0xffff0000u);
    r.z = __uint_as_float(v.y << 16);
    r.w = __uint_as_float(v.y & 0xffff0000u);
    return r;
}

// ---------------- fused CSR-bucket build ----------------
// cursor[d]: in-degree via atomic position allocation; bucket[d*CAP+pos]=src.
// cnt_out replicated 4x to cut atomic line contention.
__global__ void build_kernel(const int* __restrict__ src, const int* __restrict__ dst,
                             int* __restrict__ cursor, int* __restrict__ cnt_out_rep,
                             int* __restrict__ bucket) {
    int e = blockIdx.x * 256 + threadIdx.x;
    if (e < N_EDGES) {
        int s = src[e], d = dst[e];
        atomicAdd(&cnt_out_rep[(blockIdx.x & 3) * N_NODES + s], 1);
        int pos = atomicAdd(&cursor[d], 1);
        if (pos < CAP) bucket[d * CAP + pos] = s;
    }
}

__global__ void finalize_kernel(const int* __restrict__ cursor,
                                const int* __restrict__ cnt_out_rep,
                                float* __restrict__ isq_src, float* __restrict__ isq_dst) {
    int i = blockIdx.x * 256 + threadIdx.x;
    if (i < N_NODES) {
        int co = cnt_out_rep[i] + cnt_out_rep[N_NODES + i] +
                 cnt_out_rep[2 * N_NODES + i] + cnt_out_rep[3 * N_NODES + i];
        isq_src[i] = rsqrtf((float)max(co, 1));
        isq_dst[i] = rsqrtf((float)max(cursor[i], 1));
    }
}

// ---------------- h = emb[labels] + PE;  hs16 = bf16(h * isq_src) ----------------
__global__ void init_h_kernel(const int* __restrict__ labels, const int* __restrict__ perms,
                              const float* __restrict__ emb, const float* __restrict__ isq_src,
                              float* __restrict__ h, unsigned short* __restrict__ hs16) {
    int b = blockIdx.x;
    int g = b / NODES_PER;
    int i = b - g * NODES_PER;
    int node = g * NODES_PER + perms[b];
    int d = threadIdx.x;
    int k = d >> 1;
    float ang = (float)(i + 1) * expf((float)(2 * k) * (-9.210340371976184f / 128.0f));
    float pe = (d & 1) ? cosf(ang) : sinf(ang);
    float v = emb[labels[node] * D + d] + pe;
    h[node * D + d] = v;
    hs16[node * D + d] = (unsigned short)rne16(v * isq_src[node]);
}

// ---------------- m16[v] = bf16( isq_dst[v] * sum_{s in bucket[v]} hs16[s] ) ------------
// wave per node; QUARTER-wave (16 lanes x 16B = full 256B bf16 row) per edge.
__global__ __launch_bounds__(256) void aggregate_kernel(const unsigned short* __restrict__ hs16,
        const int* __restrict__ cursor, const int* __restrict__ bucket,
        const float* __restrict__ isq_dst, unsigned short* __restrict__ m16) {
    int node = blockIdx.x * 4 + (threadIdx.x >> 6);
    int lane = threadIdx.x & 63;
    int q = lane >> 4;          // quarter 0..3
    int col = lane & 15;        // 8-feature block
    int deg = min(cursor[node], CAP);
    int start = node * CAP;
    int end = start + deg;
    const unsigned short* hb = hs16 + col * 8;
    float a[8] = {0.f, 0.f, 0.f, 0.f, 0.f, 0.f, 0.f, 0.f};

    int e = start;
    for (; e + 8 <= end; e += 8) {
        int s0 = bucket[e + q];
        int s1 = bucket[e + 4 + q];
        uint4 v0 = *(const uint4*)&hb[s0 * D];
        uint4 v1 = *(const uint4*)&hb[s1 * D];
        float4 f0 = bf4_to_f4(make_uint2(v0.x, v0.y));
        float4 f1 = bf4_to_f4(make_uint2(v0.z, v0.w));
        float4 f2 = bf4_to_f4(make_uint2(v1.x, v1.y));
        float4 f3 = bf4_to_f4(make_uint2(v1.z, v1.w));
        a[0] += f0.x; a[1] += f0.y; a[2] += f0.z; a[3] += f0.w;
        a[4] += f1.x; a[5] += f1.y; a[6] += f1.z; a[7] += f1.w;
        a[0] += f2.x; a[1] += f2.y; a[2] += f2.z; a[3] += f2.w;
        a[4] += f3.x; a[5] += f3.y; a[6] += f3.z; a[7] += f3.w;
    }
    if (e + 4 <= end) {
        int s0 = bucket[e + q];
        uint4 v0 = *(const uint4*)&hb[s0 * D];
        float4 f0 = bf4_to_f4(make_uint2(v0.x, v0.y));
        float4 f1 = bf4_to_f4(make_uint2(v0.z, v0.w));
        a[0] += f0.x; a[1] += f0.y; a[2] += f0.z; a[3] += f0.w;
        a[4] += f1.x; a[5] += f1.y; a[6] += f1.z; a[7] += f1.w;
        e += 4;
    }
    int r = end - e;            // 0..3
    if (q < r) {
        int s0 = bucket[e + q];
        uint4 v0 = *(const uint4*)&hb[s0 * D];
        float4 f0 = bf4_to_f4(make_uint2(v0.x, v0.y));
        float4 f1 = bf4_to_f4(make_uint2(v0.z, v0.w));
        a[0] += f0.x; a[1] += f0.y; a[2] += f0.z; a[3] += f0.w;
        a[4] += f1.x; a[5] += f1.y; a[6] += f1.z; a[7] += f1.w;
    }
    // combine quarters
#pragma unroll
    for (int i = 0; i < 8; ++i) {
        a[i] += __shfl_xor(a[i], 16, 64);
        a[i] += __shfl_xor(a[i], 32, 64);
    }
    if (q == 0) {
        float wd = isq_dst[node];
        uint4 o;
        o.x = pack_bf2(a[0] * wd, a[1] * wd);
        o.y = pack_bf2(a[2] * wd, a[3] * wd);
        o.z = pack_bf2(a[4] * wd, a[5] * wd);
        o.w = pack_bf2(a[6] * wd, a[7] * wd);
        *(uint4*)&m16[node * D + col * 8] = o;
    }
}

// ------- h = relu(m @ W + b) + h : 64-row x 128-col tile, 4x8/thread, swizzled msT -------
// epilogue also writes hs16 = bf16(h_new * isq_src) unless isq == nullptr (last layer)
__global__ __launch_bounds__(256) void layer_kernel(const unsigned short* __restrict__ m16,
                                                    const float* __restrict__ W,
                                                    const float* __restrict__ bias,
                                                    float* __restrict__ h,
                                                    unsigned short* __restrict__ hs16,
                                                    const float* __restrict__ isq) {
    __shared__ float msT[128][68];
    int t = threadIdx.x;
    int rowbase = blockIdx.x * 64;

    for (int i = t; i < 2048; i += 256) {
        int row = i >> 5;
        int kc = i & 31;
        int grow = rowbase + row;
        float4 v = make_float4(0.f, 0.f, 0.f, 0.f);
        if (grow < N_NODES) v = bf4_to_f4(*(const uint2*)&m16[grow * D + kc * 4]);
        int cs = row ^ ((kc & 7) << 2);
        msT[kc * 4 + 0][cs] = v.x;
        msT[kc * 4 + 1][cs] = v.y;
        msT[kc * 4 + 2][cs] = v.z;
        msT[kc * 4 + 3][cs] = v.w;
    }
    __syncthreads();

    int tx = t & 15, ty = t >> 4;
    int c0 = tx * 8;
    int r0 = ty * 4;
    float acc[4][8];
    float4 bv0 = *(const float4*)&bias[c0];
    float4 bv1 = *(const float4*)&bias[c0 + 4];
#pragma unroll
    for (int i = 0; i < 4; ++i) {
        acc[i][0] = bv0.x; acc[i][1] = bv0.y; acc[i][2] = bv0.z; acc[i][3] = bv0.w;
        acc[i][4] = bv1.x; acc[i][5] = bv1.y; acc[i][6] = bv1.z; acc[i][7] = bv1.w;
    }
#pragma unroll 4
    for (int k = 0; k < 128; ++k) {
        int s4 = ((k >> 2) & 7) << 2;
        float4 wa = *(const float4*)&W[k * D + c0];
        float4 wb = *(const float4*)&W[k * D + c0 + 4];
        float4 ma = *(const float4*)&msT[k][r0 ^ s4];
        float mv[4] = {ma.x, ma.y, ma.z, ma.w};
        float wv[8] = {wa.x, wa.y, wa.z, wa.w, wb.x, wb.y, wb.z, wb.w};
#pragma unroll
        for (int i = 0; i < 4; ++i)
#pragma unroll
            for (int j = 0; j < 8; ++j)
                acc[i][j] += mv[i] * wv[j];
    }
#pragma unroll
    for (int i = 0; i < 4; ++i) {
        int row = rowbase + r0 + i;
        if (row < N_NODES) {
            float4 h0 = *(const float4*)&h[row * D + c0];
            float4 h1 = *(const float4*)&h[row * D + c0 + 4];
            float4 o0, o1;
            o0.x = fmaxf(acc[i][0], 0.f) + h0.x;
            o0.y = fmaxf(acc[i][1], 0.f) + h0.y;
            o0.z = fmaxf(acc[i][2], 0.f) + h0.z;
            o0.w = fmaxf(acc[i][3], 0.f) + h0.w;
            o1.x = fmaxf(acc[i][4], 0.f) + h1.x;
            o1.y = fmaxf(acc[i][5], 0.f) + h1.y;
            o1.z = fmaxf(acc[i][6], 0.f) + h1.z;
            o1.w = fmaxf(acc[i][7], 0.f) + h1.w;
            *(float4*)&h[row * D + c0] = o0;
            *(float4*)&h[row * D + c0 + 4] = o1;
            if (isq) {
                float s = isq[row];
                uint4 p;
                p.x = pack_bf2(o0.x * s, o0.y * s);
                p.y = pack_bf2(o0.z * s, o0.w * s);
                p.z = pack_bf2(o1.x * s, o1.y * s);
                p.w = pack_bf2(o1.z * s, o1.w * s);
                *(uint4*)&hs16[row * D + c0] = p;
            }
        }
    }
}

// ---------------- MLP readout: 64-row tile, 256 threads, 34.8 KB LDS ----------------
__global__ __launch_bounds__(256, 4) void readout_kernel(const float* __restrict__ h,
        const float* __restrict__ w1, const float* __restrict__ b1,
        const float* __restrict__ w2, const float* __restrict__ b2,
        const float* __restrict__ w3, const float* __restrict__ b3,
        float* __restrict__ out) {
    __shared__ float hT[128][68];
    int t = threadIdx.x;
    int rowbase = blockIdx.x * 64;
    int tx = t & 15, ty = t >> 4;
    int r0 = ty * 4;

    for (int i = t; i < 2048; i += 256) {
        int row = i >> 5;
        int kc = i & 31;
        int grow = rowbase + row;
        float4 v = (grow < N_NODES) ? *(const float4*)&h[grow * D + kc * 4]
                                    : make_float4(0.f, 0.f, 0.f, 0.f);
        int cs = row ^ ((kc & 7) << 2);
        hT[kc * 4 + 0][cs] = v.x;
        hT[kc * 4 + 1][cs] = v.y;
        hT[kc * 4 + 2][cs] = v.z;
        hT[kc * 4 + 3][cs] = v.w;
    }
    __syncthreads();

    // stage1: y1 = relu(h @ w1 + b1) : 64x64, thread tile 4x4
    float a1[4][4];
    {
        int c1 = tx * 4;
        float4 bv = *(const float4*)&b1[c1];
#pragma unroll
        for (int i = 0; i < 4; ++i) {
            a1[i][0] = bv.x; a1[i][1] = bv.y; a1[i][2] = bv.z; a1[i][3] = bv.w;
        }
#pragma unroll 2
        for (int k = 0; k < 128; ++k) {
            int s4 = ((k >> 2) & 7) << 2;
            float4 ma = *(const float4*)&hT[k][r0 ^ s4];
            float4 wv = *(const float4*)&w1[k * 64 + c1];
            float mv[4] = {ma.x, ma.y, ma.z, ma.w};
#pragma unroll
            for (int i = 0; i < 4; ++i) {
                a1[i][0] += mv[i] * wv.x;
                a1[i][1] += mv[i] * wv.y;
                a1[i][2] += mv[i] * wv.z;
                a1[i][3] += mv[i] * wv.w;
            }
        }
    }
    __syncthreads();
    {
        int c1 = tx * 4;
#pragma unroll
        for (int j = 0; j < 4; ++j) {
            int c = c1 + j;
            int cs = r0 ^ (((c >> 2) & 7) << 2);
            *(float4*)&hT[c][cs] = make_float4(fmaxf(a1[0][j], 0.f), fmaxf(a1[1][j], 0.f),
                                               fmaxf(a1[2][j], 0.f), fmaxf(a1[3][j], 0.f));
        }
    }
    __syncthreads();

    // stage2: y2 = relu(y1 @ w2 + b2) : 64x32, thread tile 4x2; y2T -> rows 64..95
    {
        int c2 = tx * 2;
        float a2[4][2];
        float2 bv = *(const float2*)&b2[c2];
#pragma unroll
        for (int i = 0; i < 4; ++i) { a2[i][0] = bv.x; a2[i][1] = bv.y; }
#pragma unroll 2
        for (int k = 0; k < 64; ++k) {
            int s4 = ((k >> 2) & 7) << 2;
            float4 ma = *(const float4*)&hT[k][r0 ^ s4];
            float2 wv = *(const float2*)&w2[k * 32 + c2];
            float mv[4] = {ma.x, ma.y, ma.z, ma.w};
#pragma unroll
            for (int i = 0; i < 4; ++i) {
                a2[i][0] += mv[i] * wv.x;
                a2[i][1] += mv[i] * wv.y;
            }
        }
#pragma unroll
        for (int j = 0; j < 2; ++j) {
            int c = c2 + j;
            int cs = r0 ^ (((c >> 2) & 7) << 2);
            *(float4*)&hT[64 + c][cs] = make_float4(fmaxf(a2[0][j], 0.f), fmaxf(a2[1][j], 0.f),
                                                    fmaxf(a2[2][j], 0.f), fmaxf(a2[3][j], 0.f));
        }
    }
    __syncthreads();

    // stage3: out = y2 @ w3 + b3 : 64x128, thread tile 4x8
    {
        int c0 = tx * 8;
        float acc[4][8];
        float4 bv0 = *(const float4*)&b3[c0];
        float4 bv1 = *(const float4*)&b3[c0 + 4];
#pragma unroll
        for (int i = 0; i < 4; ++i) {
            acc[i][0] = bv0.x; acc[i][1] = bv0.y; acc[i][2] = bv0.z; acc[i][3] = bv0.w;
            acc[i][4] = bv1.x; acc[i][5] = bv1.y; acc[i][6] = bv1.z; acc[i][7] = bv1.w;
        }
#pragma unroll 4
        for (int k = 0; k < 32; ++k) {
            int s4 = ((k >> 2) & 7) << 2;
            float4 ma = *(const float4*)&hT[64 + k][r0 ^ s4];
            float4 wa = *(const float4*)&w3[k * D + c0];
            float4 wb = *(const float4*)&w3[k * D + c0 + 4];
            float mv[4] = {ma.x, ma.y, ma.z, ma.w};
            float wv[8] = {wa.x, wa.y, wa.z, wa.w, wb.x, wb.y, wb.z, wb.w};
#pragma unroll
            for (int i = 0; i < 4; ++i)
#pragma unroll
                for (int j = 0; j < 8; ++j)
                    acc[i][j] += mv[i] * wv[j];
        }
#pragma unroll
        for (int i = 0; i < 4; ++i) {
            int row = rowbase + r0 + i;
            if (row < N_NODES) {
                *(float4*)&out[row * D + c0] =
                    make_float4(acc[i][0], acc[i][1], acc[i][2], acc[i][3]);
                *(float4*)&out[row * D + c0 + 4] =
                    make_float4(acc[i][4], acc[i][5], acc[i][6], acc[i][7]);
            }
        }
    }
}

extern "C" void kernel_launch(void* const* d_in, const int* in_sizes, int n_in,
                              void* d_out, int out_size, void* d_ws, size_t ws_size,
                              hipStream_t stream) {
    const int*   labels = (const int*)d_in[0];
    const int*   src    = (const int*)d_in[1];
    const int*   dst    = (const int*)d_in[2];
    const int*   perms  = (const int*)d_in[3];
    const float* emb    = (const float*)d_in[4];
    const float* Ws     = (const float*)d_in[5];
    const float* bs     = (const float*)d_in[6];
    const float* w1     = (const float*)d_in[7];
    const float* b1     = (const float*)d_in[8];
    const float* w2     = (const float*)d_in[9];
    const float* b2     = (const float*)d_in[10];
    const float* w3     = (const float*)d_in[11];
    const float* b3     = (const float*)d_in[12];
    float* out = (float*)d_out;

    char* p = (char*)d_ws;
    auto alloc = [&](size_t bytes) -> char* {
        char* r = p;
        p += (bytes + 255) & ~size_t(255);
        return r;
    };
    float*          h       = (float*)alloc((size_t)N_NODES * D * 4);
    unsigned short* hs16    = (unsigned short*)alloc((size_t)N_NODES * D * 2);
    unsigned short* m16     = (unsigned short*)alloc((size_t)N_NODES * D * 2);
    float*          isq_src = (float*)alloc((size_t)N_NODES * 4);
    float*          isq_dst = (float*)alloc((size_t)N_NODES * 4);
    int*            cursor  = (int*)alloc((size_t)5 * N_NODES * 4);  // cursor | cnt_out x4
    int*            cnt_rep = cursor + N_NODES;
    int*            bucket  = (int*)alloc((size_t)N_NODES * CAP * 4);

    hipMemsetAsync(cursor, 0, (size_t)5 * N_NODES * 4, stream);
    build_kernel<<<(N_EDGES + 255) / 256, 256, 0, stream>>>(src, dst, cursor, cnt_rep, bucket);
    finalize_kernel<<<(N_NODES + 255) / 256, 256, 0, stream>>>(cursor, cnt_rep,
                                                               isq_src, isq_dst);
    init_h_kernel<<<N_NODES, 128, 0, stream>>>(labels, perms, emb, isq_src, h, hs16);

    for (int l = 0; l < NLAYERS; ++l) {
        aggregate_kernel<<<N_NODES / 4, 256, 0, stream>>>(hs16, cursor, bucket, isq_dst, m16);
        layer_kernel<<<(N_NODES + 63) / 64, 256, 0, stream>>>(
            m16, Ws + (size_t)l * D * D, bs + (size_t)l * D, h, hs16,
            (l < NLAYERS - 1) ? isq_src : (const float*)nullptr);
    }
    readout_kernel<<<(N_NODES + 63) / 64, 256, 0, stream>>>(h, w1, b1, w2, b2, w3, b3, out);
}

// Round 7
// 481.592 us; speedup vs baseline: 1.6911x; 1.0698x over previous
//
#include <hip/hip_runtime.h>

#define N_NODES 50000
#define N_EDGES 800000
#define D 128
#define NLAYERS 4
#define NODES_PER 2000
#define CAP 64          // bucket capacity per node; max in-deg (Poisson 16) ~ 40

typedef __attribute__((ext_vector_type(8))) short bf16x8;   // 8 bf16 (4 VGPRs)
typedef __attribute__((ext_vector_type(4))) float f32x4;

// ---- bf16 helpers (RNE round, bit tricks) ----
__device__ inline unsigned rne16(float f) {
    unsigned u = __float_as_uint(f);
    return (u + 0x7fffu + ((u >> 16) & 1u)) >> 16;
}
__device__ inline unsigned pack_bf2(float a, float b) {
    return rne16(a) | (rne16(b) << 16);
}
__device__ inline float4 bf4_to_f4(uint2 v) {
    float4 r;
    r.x = __uint_as_float(v.x << 16);
    r.y = __uint_as_float(v.x & 0xffff0000u);
    r.z = __uint_as_float(v.y << 16);
    r.w = __uint_as_float(v.y & 0xffff0000u);
    return r;
}

// ---------------- fused CSR-bucket build (ushort payload) ----------------
__global__ void build_kernel(const int* __restrict__ src, const int* __restrict__ dst,
                             int* __restrict__ cursor, int* __restrict__ cnt_out_rep,
                             unsigned short* __restrict__ bucket) {
    int e = blockIdx.x * 256 + threadIdx.x;
    if (e < N_EDGES) {
        int s = src[e], d = dst[e];
        atomicAdd(&cnt_out_rep[(blockIdx.x & 3) * N_NODES + s], 1);
        int pos = atomicAdd(&cursor[d], 1);
        if (pos < CAP) bucket[d * CAP + pos] = (unsigned short)s;
    }
}

__global__ void finalize_kernel(const int* __restrict__ cursor,
                                const int* __restrict__ cnt_out_rep,
                                float* __restrict__ isq_src, float* __restrict__ isq_dst) {
    int i = blockIdx.x * 256 + threadIdx.x;
    if (i < N_NODES) {
        int co = cnt_out_rep[i] + cnt_out_rep[N_NODES + i] +
                 cnt_out_rep[2 * N_NODES + i] + cnt_out_rep[3 * N_NODES + i];
        isq_src[i] = rsqrtf((float)max(co, 1));
        isq_dst[i] = rsqrtf((float)max(cursor[i], 1));
    }
}

// ---------------- Wt[l][n][k] = bf16(W[l][k][n]) ----------------
__global__ void transpose_w_kernel(const float* __restrict__ Ws,
                                   unsigned short* __restrict__ Wt) {
    int l = blockIdx.x;
    const float* W = Ws + (size_t)l * D * D;
    unsigned short* T = Wt + (size_t)l * D * D;
    for (int i = threadIdx.x; i < D * D; i += 256) {
        int k = i >> 7, n = i & 127;
        T[n * D + k] = (unsigned short)rne16(W[i]);
    }
}

// ---------------- h = emb[labels] + PE;  hs16 = bf16(h * isq_src) ----------------
__global__ void init_h_kernel(const int* __restrict__ labels, const int* __restrict__ perms,
                              const float* __restrict__ emb, const float* __restrict__ isq_src,
                              float* __restrict__ h, unsigned short* __restrict__ hs16) {
    int b = blockIdx.x;
    int g = b / NODES_PER;
    int i = b - g * NODES_PER;
    int node = g * NODES_PER + perms[b];
    int d = threadIdx.x;
    int k = d >> 1;
    float ang = (float)(i + 1) * expf((float)(2 * k) * (-9.210340371976184f / 128.0f));
    float pe = (d & 1) ? cosf(ang) : sinf(ang);
    float v = emb[labels[node] * D + d] + pe;
    h[node * D + d] = v;
    hs16[node * D + d] = (unsigned short)rne16(v * isq_src[node]);
}

// ---------------- m16[v] = bf16( isq_dst[v] * sum_{s in bucket[v]} hs16[s] ) ------------
// wave per node; QUARTER-wave (16 lanes x 16B = full 256B bf16 row) per edge.
__global__ __launch_bounds__(256) void aggregate_kernel(const unsigned short* __restrict__ hs16,
        const int* __restrict__ cursor, const unsigned short* __restrict__ bucket,
        const float* __restrict__ isq_dst, unsigned short* __restrict__ m16) {
    int node = blockIdx.x * 4 + (threadIdx.x >> 6);
    int lane = threadIdx.x & 63;
    int q = lane >> 4;          // quarter 0..3
    int col = lane & 15;        // 8-feature block
    int deg = min(cursor[node], CAP);
    int start = node * CAP;
    int end = start + deg;
    const unsigned short* hb = hs16 + col * 8;
    float a[8] = {0.f, 0.f, 0.f, 0.f, 0.f, 0.f, 0.f, 0.f};

    int e = start;
    for (; e + 8 <= end; e += 8) {
        int s0 = bucket[e + q];
        int s1 = bucket[e + 4 + q];
        uint4 v0 = *(const uint4*)&hb[s0 * D];
        uint4 v1 = *(const uint4*)&hb[s1 * D];
        float4 f0 = bf4_to_f4(make_uint2(v0.x, v0.y));
        float4 f1 = bf4_to_f4(make_uint2(v0.z, v0.w));
        float4 f2 = bf4_to_f4(make_uint2(v1.x, v1.y));
        float4 f3 = bf4_to_f4(make_uint2(v1.z, v1.w));
        a[0] += f0.x; a[1] += f0.y; a[2] += f0.z; a[3] += f0.w;
        a[4] += f1.x; a[5] += f1.y; a[6] += f1.z; a[7] += f1.w;
        a[0] += f2.x; a[1] += f2.y; a[2] += f2.z; a[3] += f2.w;
        a[4] += f3.x; a[5] += f3.y; a[6] += f3.z; a[7] += f3.w;
    }
    if (e + 4 <= end) {
        int s0 = bucket[e + q];
        uint4 v0 = *(const uint4*)&hb[s0 * D];
        float4 f0 = bf4_to_f4(make_uint2(v0.x, v0.y));
        float4 f1 = bf4_to_f4(make_uint2(v0.z, v0.w));
        a[0] += f0.x; a[1] += f0.y; a[2] += f0.z; a[3] += f0.w;
        a[4] += f1.x; a[5] += f1.y; a[6] += f1.z; a[7] += f1.w;
        e += 4;
    }
    int r = end - e;            // 0..3
    if (q < r) {
        int s0 = bucket[e + q];
        uint4 v0 = *(const uint4*)&hb[s0 * D];
        float4 f0 = bf4_to_f4(make_uint2(v0.x, v0.y));
        float4 f1 = bf4_to_f4(make_uint2(v0.z, v0.w));
        a[0] += f0.x; a[1] += f0.y; a[2] += f0.z; a[3] += f0.w;
        a[4] += f1.x; a[5] += f1.y; a[6] += f1.z; a[7] += f1.w;
    }
#pragma unroll
    for (int i = 0; i < 8; ++i) {
        a[i] += __shfl_xor(a[i], 16, 64);
        a[i] += __shfl_xor(a[i], 32, 64);
    }
    if (q == 0) {
        float wd = isq_dst[node];
        uint4 o;
        o.x = pack_bf2(a[0] * wd, a[1] * wd);
        o.y = pack_bf2(a[2] * wd, a[3] * wd);
        o.z = pack_bf2(a[4] * wd, a[5] * wd);
        o.w = pack_bf2(a[6] * wd, a[7] * wd);
        *(uint4*)&m16[node * D + col * 8] = o;
    }
}

// ------- h = relu(m @ W + b) + h via MFMA, no LDS --------
// block = 4 waves; wave owns 16 rows x 128 cols. A = m16 rows (bf16), B = Wt[n][k] (bf16).
// mfma_f32_16x16x32_bf16: A-frag lane: row=lane&15, k=(lane>>4)*8+j (16B contiguous).
//                          B-frag lane: col=lane&15, k=(lane>>4)*8+j (16B contiguous in Wt).
//                          C/D: col=lane&15, row=(lane>>4)*4+reg.
__global__ __launch_bounds__(256) void layer_mfma_kernel(const unsigned short* __restrict__ m16,
        const unsigned short* __restrict__ Wt, const float* __restrict__ bias,
        float* __restrict__ h, unsigned short* __restrict__ hs16,
        const float* __restrict__ isq) {
    int wave = threadIdx.x >> 6;
    int lane = threadIdx.x & 63;
    int rowbase = blockIdx.x * 64 + wave * 16;
    int col16 = lane & 15;
    int kq8 = (lane >> 4) * 8;

    int arow = min(rowbase + col16, N_NODES - 1);   // clamp keeps loads in-bounds
    bf16x8 afrag[4];
#pragma unroll
    for (int kk = 0; kk < 4; ++kk)
        afrag[kk] = *(const bf16x8*)&m16[(size_t)arow * D + kk * 32 + kq8];

    int orow0 = rowbase + (lane >> 4) * 4;

#pragma unroll 2
    for (int nt = 0; nt < 8; ++nt) {
        int ncol = nt * 16 + col16;
        float bv = bias[ncol];
        f32x4 acc = {bv, bv, bv, bv};
#pragma unroll
        for (int kk = 0; kk < 4; ++kk) {
            bf16x8 bfrag = *(const bf16x8*)&Wt[(size_t)ncol * D + kk * 32 + kq8];
            acc = __builtin_amdgcn_mfma_f32_16x16x32_bf16(afrag[kk], bfrag, acc, 0, 0, 0);
        }
#pragma unroll
        for (int r = 0; r < 4; ++r) {
            int row = orow0 + r;
            if (row < N_NODES) {
                size_t idx = (size_t)row * D + ncol;
                float o = fmaxf(acc[r], 0.f) + h[idx];
                h[idx] = o;
                if (isq) hs16[idx] = (unsigned short)rne16(o * isq[row]);
            }
        }
    }
}

// ---------------- MLP readout: 64-row tile, 256 threads, 34.8 KB LDS ----------------
__global__ __launch_bounds__(256, 4) void readout_kernel(const float* __restrict__ h,
        const float* __restrict__ w1, const float* __restrict__ b1,
        const float* __restrict__ w2, const float* __restrict__ b2,
        const float* __restrict__ w3, const float* __restrict__ b3,
        float* __restrict__ out) {
    __shared__ float hT[128][68];
    int t = threadIdx.x;
    int rowbase = blockIdx.x * 64;
    int tx = t & 15, ty = t >> 4;
    int r0 = ty * 4;

    for (int i = t; i < 2048; i += 256) {
        int row = i >> 5;
        int kc = i & 31;
        int grow = rowbase + row;
        float4 v = (grow < N_NODES) ? *(const float4*)&h[grow * D + kc * 4]
                                    : make_float4(0.f, 0.f, 0.f, 0.f);
        int cs = row ^ ((kc & 7) << 2);
        hT[kc * 4 + 0][cs] = v.x;
        hT[kc * 4 + 1][cs] = v.y;
        hT[kc * 4 + 2][cs] = v.z;
        hT[kc * 4 + 3][cs] = v.w;
    }
    __syncthreads();

    // stage1: y1 = relu(h @ w1 + b1) : 64x64, thread tile 4x4
    float a1[4][4];
    {
        int c1 = tx * 4;
        float4 bv = *(const float4*)&b1[c1];
#pragma unroll
        for (int i = 0; i < 4; ++i) {
            a1[i][0] = bv.x; a1[i][1] = bv.y; a1[i][2] = bv.z; a1[i][3] = bv.w;
        }
#pragma unroll 2
        for (int k = 0; k < 128; ++k) {
            int s4 = ((k >> 2) & 7) << 2;
            float4 ma = *(const float4*)&hT[k][r0 ^ s4];
            float4 wv = *(const float4*)&w1[k * 64 + c1];
            float mv[4] = {ma.x, ma.y, ma.z, ma.w};
#pragma unroll
            for (int i = 0; i < 4; ++i) {
                a1[i][0] += mv[i] * wv.x;
                a1[i][1] += mv[i] * wv.y;
                a1[i][2] += mv[i] * wv.z;
                a1[i][3] += mv[i] * wv.w;
            }
        }
    }
    __syncthreads();
    {
        int c1 = tx * 4;
#pragma unroll
        for (int j = 0; j < 4; ++j) {
            int c = c1 + j;
            int cs = r0 ^ (((c >> 2) & 7) << 2);
            *(float4*)&hT[c][cs] = make_float4(fmaxf(a1[0][j], 0.f), fmaxf(a1[1][j], 0.f),
                                               fmaxf(a1[2][j], 0.f), fmaxf(a1[3][j], 0.f));
        }
    }
    __syncthreads();

    // stage2: y2 = relu(y1 @ w2 + b2) : 64x32, thread tile 4x2; y2T -> rows 64..95
    {
        int c2 = tx * 2;
        float a2[4][2];
        float2 bv = *(const float2*)&b2[c2];
#pragma unroll
        for (int i = 0; i < 4; ++i) { a2[i][0] = bv.x; a2[i][1] = bv.y; }
#pragma unroll 2
        for (int k = 0; k < 64; ++k) {
            int s4 = ((k >> 2) & 7) << 2;
            float4 ma = *(const float4*)&hT[k][r0 ^ s4];
            float2 wv = *(const float2*)&w2[k * 32 + c2];
            float mv[4] = {ma.x, ma.y, ma.z, ma.w};
#pragma unroll
            for (int i = 0; i < 4; ++i) {
                a2[i][0] += mv[i] * wv.x;
                a2[i][1] += mv[i] * wv.y;
            }
        }
#pragma unroll
        for (int j = 0; j < 2; ++j) {
            int c = c2 + j;
            int cs = r0 ^ (((c >> 2) & 7) << 2);
            *(float4*)&hT[64 + c][cs] = make_float4(fmaxf(a2[0][j], 0.f), fmaxf(a2[1][j], 0.f),
                                                    fmaxf(a2[2][j], 0.f), fmaxf(a2[3][j], 0.f));
        }
    }
    __syncthreads();

    // stage3: out = y2 @ w3 + b3 : 64x128, thread tile 4x8
    {
        int c0 = tx * 8;
        float acc[4][8];
        float4 bv0 = *(const float4*)&b3[c0];
        float4 bv1 = *(const float4*)&b3[c0 + 4];
#pragma unroll
        for (int i = 0; i < 4; ++i) {
            acc[i][0] = bv0.x; acc[i][1] = bv0.y; acc[i][2] = bv0.z; acc[i][3] = bv0.w;
            acc[i][4] = bv1.x; acc[i][5] = bv1.y; acc[i][6] = bv1.z; acc[i][7] = bv1.w;
        }
#pragma unroll 4
        for (int k = 0; k < 32; ++k) {
            int s4 = ((k >> 2) & 7) << 2;
            float4 ma = *(const float4*)&hT[64 + k][r0 ^ s4];
            float4 wa = *(const float4*)&w3[k * D + c0];
            float4 wb = *(const float4*)&w3[k * D + c0 + 4];
            float mv[4] = {ma.x, ma.y, ma.z, ma.w};
            float wv[8] = {wa.x, wa.y, wa.z, wa.w, wb.x, wb.y, wb.z, wb.w};
#pragma unroll
            for (int i = 0; i < 4; ++i)
#pragma unroll
                for (int j = 0; j < 8; ++j)
                    acc[i][j] += mv[i] * wv[j];
        }
#pragma unroll
        for (int i = 0; i < 4; ++i) {
            int row = rowbase + r0 + i;
            if (row < N_NODES) {
                *(float4*)&out[row * D + c0] =
                    make_float4(acc[i][0], acc[i][1], acc[i][2], acc[i][3]);
                *(float4*)&out[row * D + c0 + 4] =
                    make_float4(acc[i][4], acc[i][5], acc[i][6], acc[i][7]);
            }
        }
    }
}

extern "C" void kernel_launch(void* const* d_in, const int* in_sizes, int n_in,
                              void* d_out, int out_size, void* d_ws, size_t ws_size,
                              hipStream_t stream) {
    const int*   labels = (const int*)d_in[0];
    const int*   src    = (const int*)d_in[1];
    const int*   dst    = (const int*)d_in[2];
    const int*   perms  = (const int*)d_in[3];
    const float* emb    = (const float*)d_in[4];
    const float* Ws     = (const float*)d_in[5];
    const float* bs     = (const float*)d_in[6];
    const float* w1     = (const float*)d_in[7];
    const float* b1     = (const float*)d_in[8];
    const float* w2     = (const float*)d_in[9];
    const float* b2     = (const float*)d_in[10];
    const float* w3     = (const float*)d_in[11];
    const float* b3     = (const float*)d_in[12];
    float* out = (float*)d_out;

    char* p = (char*)d_ws;
    auto alloc = [&](size_t bytes) -> char* {
        char* r = p;
        p += (bytes + 255) & ~size_t(255);
        return r;
    };
    float*          h       = (float*)alloc((size_t)N_NODES * D * 4);
    unsigned short* hs16    = (unsigned short*)alloc((size_t)N_NODES * D * 2);
    unsigned short* m16     = (unsigned short*)alloc((size_t)N_NODES * D * 2);
    unsigned short* Wt      = (unsigned short*)alloc((size_t)NLAYERS * D * D * 2);
    float*          isq_src = (float*)alloc((size_t)N_NODES * 4);
    float*          isq_dst = (float*)alloc((size_t)N_NODES * 4);
    int*            cursor  = (int*)alloc((size_t)5 * N_NODES * 4);  // cursor | cnt_out x4
    int*            cnt_rep = cursor + N_NODES;
    unsigned short* bucket  = (unsigned short*)alloc((size_t)N_NODES * CAP * 2);

    hipMemsetAsync(cursor, 0, (size_t)5 * N_NODES * 4, stream);
    transpose_w_kernel<<<NLAYERS, 256, 0, stream>>>(Ws, Wt);
    build_kernel<<<(N_EDGES + 255) / 256, 256, 0, stream>>>(src, dst, cursor, cnt_rep, bucket);
    finalize_kernel<<<(N_NODES + 255) / 256, 256, 0, stream>>>(cursor, cnt_rep,
                                                               isq_src, isq_dst);
    init_h_kernel<<<N_NODES, 128, 0, stream>>>(labels, perms, emb, isq_src, h, hs16);

    for (int l = 0; l < NLAYERS; ++l) {
        aggregate_kernel<<<N_NODES / 4, 256, 0, stream>>>(hs16, cursor, bucket, isq_dst, m16);
        layer_mfma_kernel<<<(N_NODES + 63) / 64, 256, 0, stream>>>(
            m16, Wt + (size_t)l * D * D, bs + (size_t)l * D, h, hs16,
            (l < NLAYERS - 1) ? isq_src : (const float*)nullptr);
    }
    readout_kernel<<<(N_NODES + 63) / 64, 256, 0, stream>>>(h, w1, b1, w2, b2, w3, b3, out);
}

// Round 8
// 455.266 us; speedup vs baseline: 1.7888x; 1.0578x over previous
//
#include <hip/hip_runtime.h>

#define N_NODES 50000
#define N_EDGES 800000
#define D 128
#define NLAYERS 4
#define NODES_PER 2000
#define CAP 64          // bucket capacity per node; max in-deg (Poisson 16) ~ 40
#define NB_BUILD 3125   // (N_EDGES+255)/256
#define NB_INIT 25000   // 2 nodes per 256-thread block

typedef __attribute__((ext_vector_type(8))) short bf16x8;   // 8 bf16 (4 VGPRs)
typedef __attribute__((ext_vector_type(4))) float f32x4;

// ---- bf16 helpers (RNE round, bit tricks) ----
__device__ inline unsigned rne16(float f) {
    unsigned u = __float_as_uint(f);
    return (u + 0x7fffu + ((u >> 16) & 1u)) >> 16;
}
__device__ inline unsigned pack_bf2(float a, float b) {
    return rne16(a) | (rne16(b) << 16);
}
__device__ inline float4 bf4_to_f4(uint2 v) {
    float4 r;
    r.x = __uint_as_float(v.x << 16);
    r.y = __uint_as_float(v.x & 0xffff0000u);
    r.z = __uint_as_float(v.y << 16);
    r.w = __uint_as_float(v.y & 0xffff0000u);
    return r;
}

// ---------------- fused: bucket build | h init (emb+PE) | weight transposes ----------------
__global__ void build_init_kernel(const int* __restrict__ src, const int* __restrict__ dst,
                                  int* __restrict__ cursor, int* __restrict__ cnt_out_rep,
                                  unsigned short* __restrict__ bucket,
                                  const int* __restrict__ labels, const int* __restrict__ perms,
                                  const float* __restrict__ emb, float* __restrict__ h,
                                  const float* __restrict__ Ws, unsigned short* __restrict__ Wt,
                                  const float* __restrict__ w1, unsigned short* __restrict__ w1t,
                                  const float* __restrict__ w2, unsigned short* __restrict__ w2t,
                                  const float* __restrict__ w3, unsigned short* __restrict__ w3t) {
    int b = blockIdx.x;
    if (b < NB_BUILD) {
        int e = b * 256 + threadIdx.x;
        if (e < N_EDGES) {
            int s = src[e], d = dst[e];
            atomicAdd(&cnt_out_rep[(b & 3) * N_NODES + s], 1);
            int pos = atomicAdd(&cursor[d], 1);
            if (pos < CAP) bucket[d * CAP + pos] = (unsigned short)s;
        }
    } else if (b < NB_BUILD + NB_INIT) {
        int j = (b - NB_BUILD) * 2 + (threadIdx.x >> 7);   // 0..49999 enumerates (g,i)
        int d = threadIdx.x & 127;
        int g = j / NODES_PER;
        int i = j - g * NODES_PER;
        int node = g * NODES_PER + perms[j];
        int k = d >> 1;
        float ang = (float)(i + 1) * expf((float)(2 * k) * (-9.210340371976184f / 128.0f));
        float pe = (d & 1) ? cosf(ang) : sinf(ang);
        h[node * D + d] = emb[labels[node] * D + d] + pe;
    } else {
        int tb = b - NB_BUILD - NB_INIT;
        if (tb < NLAYERS) {           // Wt[l][n][k] = bf16(W[l][k][n]), 128x128
            const float* W = Ws + (size_t)tb * D * D;
            unsigned short* T = Wt + (size_t)tb * D * D;
            for (int i = threadIdx.x; i < D * D; i += 256) {
                int k = i >> 7, n = i & 127;
                T[n * D + k] = (unsigned short)rne16(W[i]);
            }
        } else if (tb == NLAYERS) {   // w1 [128][64] -> w1t [64][128]
            for (int i = threadIdx.x; i < 128 * 64; i += 256) {
                int k = i >> 6, n = i & 63;
                w1t[n * 128 + k] = (unsigned short)rne16(w1[i]);
            }
        } else if (tb == NLAYERS + 1) { // w2 [64][32] -> w2t [32][64]
            for (int i = threadIdx.x; i < 64 * 32; i += 256) {
                int k = i >> 5, n = i & 31;
                w2t[n * 64 + k] = (unsigned short)rne16(w2[i]);
            }
        } else {                       // w3 [32][128] -> w3t [128][32]
            for (int i = threadIdx.x; i < 32 * 128; i += 256) {
                int k = i >> 7, n = i & 127;
                w3t[n * 32 + k] = (unsigned short)rne16(w3[i]);
            }
        }
    }
}

__global__ void finalize_kernel(const int* __restrict__ cursor,
                                const int* __restrict__ cnt_out_rep,
                                float* __restrict__ isq_src, float* __restrict__ isq_dst) {
    int i = blockIdx.x * 256 + threadIdx.x;
    if (i < N_NODES) {
        int co = cnt_out_rep[i] + cnt_out_rep[N_NODES + i] +
                 cnt_out_rep[2 * N_NODES + i] + cnt_out_rep[3 * N_NODES + i];
        isq_src[i] = rsqrtf((float)max(co, 1));
        isq_dst[i] = rsqrtf((float)max(cursor[i], 1));
    }
}

// ---------------- hs16 = bf16(h * isq_src) ----------------
__global__ void hs16_kernel(const float* __restrict__ h, const float* __restrict__ isq_src,
                            unsigned short* __restrict__ hs16) {
    int gid = blockIdx.x * 256 + threadIdx.x;   // 800000 threads, 8 elems each
    int row = gid >> 4;
    int c8 = (gid & 15) * 8;
    float s = isq_src[row];
    size_t idx = (size_t)row * D + c8;
    float4 v0 = *(const float4*)&h[idx];
    float4 v1 = *(const float4*)&h[idx + 4];
    uint4 o;
    o.x = pack_bf2(v0.x * s, v0.y * s);
    o.y = pack_bf2(v0.z * s, v0.w * s);
    o.z = pack_bf2(v1.x * s, v1.y * s);
    o.w = pack_bf2(v1.z * s, v1.w * s);
    *(uint4*)&hs16[idx] = o;
}

// ---------------- m16[v] = bf16( isq_dst[v] * sum_{s in bucket[v]} hs16[s] ) ------------
// wave per node; QUARTER-wave (16 lanes x 16B = full 256B bf16 row) per edge.
__global__ __launch_bounds__(256) void aggregate_kernel(const unsigned short* __restrict__ hs16,
        const int* __restrict__ cursor, const unsigned short* __restrict__ bucket,
        const float* __restrict__ isq_dst, unsigned short* __restrict__ m16) {
    int node = blockIdx.x * 4 + (threadIdx.x >> 6);
    int lane = threadIdx.x & 63;
    int q = lane >> 4;          // quarter 0..3
    int col = lane & 15;        // 8-feature block
    int deg = min(cursor[node], CAP);
    int start = node * CAP;
    int end = start + deg;
    const unsigned short* hb = hs16 + col * 8;
    float a[8] = {0.f, 0.f, 0.f, 0.f, 0.f, 0.f, 0.f, 0.f};

    int e = start;
    for (; e + 8 <= end; e += 8) {
        int s0 = bucket[e + q];
        int s1 = bucket[e + 4 + q];
        uint4 v0 = *(const uint4*)&hb[s0 * D];
        uint4 v1 = *(const uint4*)&hb[s1 * D];
        float4 f0 = bf4_to_f4(make_uint2(v0.x, v0.y));
        float4 f1 = bf4_to_f4(make_uint2(v0.z, v0.w));
        float4 f2 = bf4_to_f4(make_uint2(v1.x, v1.y));
        float4 f3 = bf4_to_f4(make_uint2(v1.z, v1.w));
        a[0] += f0.x; a[1] += f0.y; a[2] += f0.z; a[3] += f0.w;
        a[4] += f1.x; a[5] += f1.y; a[6] += f1.z; a[7] += f1.w;
        a[0] += f2.x; a[1] += f2.y; a[2] += f2.z; a[3] += f2.w;
        a[4] += f3.x; a[5] += f3.y; a[6] += f3.z; a[7] += f3.w;
    }
    if (e + 4 <= end) {
        int s0 = bucket[e + q];
        uint4 v0 = *(const uint4*)&hb[s0 * D];
        float4 f0 = bf4_to_f4(make_uint2(v0.x, v0.y));
        float4 f1 = bf4_to_f4(make_uint2(v0.z, v0.w));
        a[0] += f0.x; a[1] += f0.y; a[2] += f0.z; a[3] += f0.w;
        a[4] += f1.x; a[5] += f1.y; a[6] += f1.z; a[7] += f1.w;
        e += 4;
    }
    int r = end - e;            // 0..3
    if (q < r) {
        int s0 = bucket[e + q];
        uint4 v0 = *(const uint4*)&hb[s0 * D];
        float4 f0 = bf4_to_f4(make_uint2(v0.x, v0.y));
        float4 f1 = bf4_to_f4(make_uint2(v0.z, v0.w));
        a[0] += f0.x; a[1] += f0.y; a[2] += f0.z; a[3] += f0.w;
        a[4] += f1.x; a[5] += f1.y; a[6] += f1.z; a[7] += f1.w;
    }
#pragma unroll
    for (int i = 0; i < 8; ++i) {
        a[i] += __shfl_xor(a[i], 16, 64);
        a[i] += __shfl_xor(a[i], 32, 64);
    }
    if (q == 0) {
        float wd = isq_dst[node];
        uint4 o;
        o.x = pack_bf2(a[0] * wd, a[1] * wd);
        o.y = pack_bf2(a[2] * wd, a[3] * wd);
        o.z = pack_bf2(a[4] * wd, a[5] * wd);
        o.w = pack_bf2(a[6] * wd, a[7] * wd);
        *(uint4*)&m16[node * D + col * 8] = o;
    }
}

// ------- h = relu(m @ W + b) + h via MFMA, no LDS --------
// Always writes bf16 shadow: scaled by isq (next layer's gather) or unscaled (readout input).
__global__ __launch_bounds__(256) void layer_mfma_kernel(const unsigned short* __restrict__ m16,
        const unsigned short* __restrict__ Wt, const float* __restrict__ bias,
        float* __restrict__ h, unsigned short* __restrict__ hs16,
        const float* __restrict__ isq) {
    int wave = threadIdx.x >> 6;
    int lane = threadIdx.x & 63;
    int rowbase = blockIdx.x * 64 + wave * 16;
    int col16 = lane & 15;
    int kq8 = (lane >> 4) * 8;

    int arow = min(rowbase + col16, N_NODES - 1);
    bf16x8 afrag[4];
#pragma unroll
    for (int kk = 0; kk < 4; ++kk)
        afrag[kk] = *(const bf16x8*)&m16[(size_t)arow * D + kk * 32 + kq8];

    int orow0 = rowbase + (lane >> 4) * 4;

#pragma unroll 2
    for (int nt = 0; nt < 8; ++nt) {
        int ncol = nt * 16 + col16;
        float bv = bias[ncol];
        f32x4 acc = {bv, bv, bv, bv};
#pragma unroll
        for (int kk = 0; kk < 4; ++kk) {
            bf16x8 bfrag = *(const bf16x8*)&Wt[(size_t)ncol * D + kk * 32 + kq8];
            acc = __builtin_amdgcn_mfma_f32_16x16x32_bf16(afrag[kk], bfrag, acc, 0, 0, 0);
        }
#pragma unroll
        for (int r = 0; r < 4; ++r) {
            int row = orow0 + r;
            if (row < N_NODES) {
                size_t idx = (size_t)row * D + ncol;
                float o = fmaxf(acc[r], 0.f) + h[idx];
                h[idx] = o;
                float s = isq ? isq[row] : 1.0f;
                hs16[idx] = (unsigned short)rne16(o * s);
            }
        }
    }
}

// ---------------- MFMA MLP readout: 64 rows/block (16/wave), bf16 weights ----------------
// A-frag: row=lane&15, k=(lane>>4)*8+j.  C/D: col=lane&15, row=(lane>>4)*4+r.
// Stage outputs bounce through per-wave LDS (C-layout != A-layout).
__global__ __launch_bounds__(256) void readout_mfma_kernel(const unsigned short* __restrict__ h16,
        const unsigned short* __restrict__ w1t, const float* __restrict__ b1,
        const unsigned short* __restrict__ w2t, const float* __restrict__ b2,
        const unsigned short* __restrict__ w3t, const float* __restrict__ b3,
        float* __restrict__ out) {
    __shared__ __align__(16) unsigned short y1s[4][16][72];   // 72 = 64 + pad
    __shared__ __align__(16) unsigned short y2s[4][16][40];   // 40 = 32 + pad
    int wave = threadIdx.x >> 6;
    int lane = threadIdx.x & 63;
    int rowbase = blockIdx.x * 64 + wave * 16;
    int c16 = lane & 15;
    int kq8 = (lane >> 4) * 8;
    int rt0 = (lane >> 4) * 4;

    int arow = min(rowbase + c16, N_NODES - 1);
    bf16x8 af[4];
#pragma unroll
    for (int kk = 0; kk < 4; ++kk)
        af[kk] = *(const bf16x8*)&h16[(size_t)arow * D + kk * 32 + kq8];

    // stage1: y1 = relu(h @ w1 + b1), 16x64
#pragma unroll
    for (int nt = 0; nt < 4; ++nt) {
        int ncol = nt * 16 + c16;
        float bv = b1[ncol];
        f32x4 acc = {bv, bv, bv, bv};
#pragma unroll
        for (int kk = 0; kk < 4; ++kk) {
            bf16x8 bfrag = *(const bf16x8*)&w1t[(size_t)ncol * 128 + kk * 32 + kq8];
            acc = __builtin_amdgcn_mfma_f32_16x16x32_bf16(af[kk], bfrag, acc, 0, 0, 0);
        }
#pragma unroll
        for (int r = 0; r < 4; ++r)
            y1s[wave][rt0 + r][ncol] = (unsigned short)rne16(fmaxf(acc[r], 0.f));
    }

    // stage2: y2 = relu(y1 @ w2 + b2), 16x32 (same-wave LDS dep; compiler waits lgkmcnt)
    bf16x8 a2[2];
#pragma unroll
    for (int kk = 0; kk < 2; ++kk)
        a2[kk] = *(const bf16x8*)&y1s[wave][c16][kk * 32 + kq8];
#pragma unroll
    for (int nt = 0; nt < 2; ++nt) {
        int ncol = nt * 16 + c16;
        float bv = b2[ncol];
        f32x4 acc = {bv, bv, bv, bv};
#pragma unroll
        for (int kk = 0; kk < 2; ++kk) {
            bf16x8 bfrag = *(const bf16x8*)&w2t[(size_t)ncol * 64 + kk * 32 + kq8];
            acc = __builtin_amdgcn_mfma_f32_16x16x32_bf16(a2[kk], bfrag, acc, 0, 0, 0);
        }
#pragma unroll
        for (int r = 0; r < 4; ++r)
            y2s[wave][rt0 + r][ncol] = (unsigned short)rne16(fmaxf(acc[r], 0.f));
    }

    // stage3: out = y2 @ w3 + b3, 16x128, K=32 exactly one MFMA per col-tile
    bf16x8 a3 = *(const bf16x8*)&y2s[wave][c16][kq8];
#pragma unroll 2
    for (int nt = 0; nt < 8; ++nt) {
        int ncol = nt * 16 + c16;
        float bv = b3[ncol];
        f32x4 acc = {bv, bv, bv, bv};
        bf16x8 bfrag = *(const bf16x8*)&w3t[(size_t)ncol * 32 + kq8];
        acc = __builtin_amdgcn_mfma_f32_16x16x32_bf16(a3, bfrag, acc, 0, 0, 0);
#pragma unroll
        for (int r = 0; r < 4; ++r) {
            int row = rowbase + rt0 + r;
            if (row < N_NODES) out[(size_t)row * D + ncol] = acc[r];
        }
    }
}

extern "C" void kernel_launch(void* const* d_in, const int* in_sizes, int n_in,
                              void* d_out, int out_size, void* d_ws, size_t ws_size,
                              hipStream_t stream) {
    const int*   labels = (const int*)d_in[0];
    const int*   src    = (const int*)d_in[1];
    const int*   dst    = (const int*)d_in[2];
    const int*   perms  = (const int*)d_in[3];
    const float* emb    = (const float*)d_in[4];
    const float* Ws     = (const float*)d_in[5];
    const float* bs     = (const float*)d_in[6];
    const float* w1     = (const float*)d_in[7];
    const float* b1     = (const float*)d_in[8];
    const float* w2     = (const float*)d_in[9];
    const float* b2     = (const float*)d_in[10];
    const float* w3     = (const float*)d_in[11];
    const float* b3     = (const float*)d_in[12];
    float* out = (float*)d_out;

    char* p = (char*)d_ws;
    auto alloc = [&](size_t bytes) -> char* {
        char* r = p;
        p += (bytes + 255) & ~size_t(255);
        return r;
    };
    float*          h       = (float*)alloc((size_t)N_NODES * D * 4);
    unsigned short* hs16    = (unsigned short*)alloc((size_t)N_NODES * D * 2);
    unsigned short* m16     = (unsigned short*)alloc((size_t)N_NODES * D * 2);
    unsigned short* Wt      = (unsigned short*)alloc((size_t)NLAYERS * D * D * 2);
    unsigned short* w1t     = (unsigned short*)alloc((size_t)64 * 128 * 2);
    unsigned short* w2t     = (unsigned short*)alloc((size_t)32 * 64 * 2);
    unsigned short* w3t     = (unsigned short*)alloc((size_t)128 * 32 * 2);
    float*          isq_src = (float*)alloc((size_t)N_NODES * 4);
    float*          isq_dst = (float*)alloc((size_t)N_NODES * 4);
    int*            cursor  = (int*)alloc((size_t)5 * N_NODES * 4);  // cursor | cnt_out x4
    int*            cnt_rep = cursor + N_NODES;
    unsigned short* bucket  = (unsigned short*)alloc((size_t)N_NODES * CAP * 2);

    hipMemsetAsync(cursor, 0, (size_t)5 * N_NODES * 4, stream);
    build_init_kernel<<<NB_BUILD + NB_INIT + NLAYERS + 3, 256, 0, stream>>>(
        src, dst, cursor, cnt_rep, bucket,
        labels, perms, emb, h,
        Ws, Wt, w1, w1t, w2, w2t, w3, w3t);
    finalize_kernel<<<(N_NODES + 255) / 256, 256, 0, stream>>>(cursor, cnt_rep,
                                                               isq_src, isq_dst);
    hs16_kernel<<<3125, 256, 0, stream>>>(h, isq_src, hs16);

    for (int l = 0; l < NLAYERS; ++l) {
        aggregate_kernel<<<N_NODES / 4, 256, 0, stream>>>(hs16, cursor, bucket, isq_dst, m16);
        layer_mfma_kernel<<<(N_NODES + 63) / 64, 256, 0, stream>>>(
            m16, Wt + (size_t)l * D * D, bs + (size_t)l * D, h, hs16,
            (l < NLAYERS - 1) ? isq_src : (const float*)nullptr);
    }
    readout_mfma_kernel<<<(N_NODES + 63) / 64, 256, 0, stream>>>(
        hs16, w1t, b1, w2t, b2, w3t, b3, out);
}